// Round 4
// baseline (1624.875 us; speedup 1.0000x reference)
//
#include <hip/hip_runtime.h>

typedef __attribute__((ext_vector_type(8))) _Float16 f16x8;
typedef __attribute__((ext_vector_type(4))) _Float16 f16x4;
typedef __attribute__((ext_vector_type(4))) float f32x4;

#define DI __device__ __forceinline__

DI f32x4 mfma16(f16x8 a, f16x8 b, f32x4 c) {
    return __builtin_amdgcn_mfma_f32_16x16x32_f16(a, b, c, 0, 0, 0);
}

// Load weight fragments for 4 n-tiles x NK k-steps. wt is W^T [N][Kp] f16 row-major.
// A-operand layout: lane i=(lane&15) holds row n, k = q*8 + j (j=0..7), plus ks*32.
template <int NK>
DI void load_wf4(const _Float16* __restrict__ wt, int Kp, int nbase, int l16, int q,
                 f16x8 f[NK][4]) {
#pragma unroll
    for (int nt = 0; nt < 4; ++nt) {
        int n = nbase + nt * 16 + l16;
#pragma unroll
        for (int ks = 0; ks < NK; ++ks)
            f[ks][nt] = *(const f16x8*)(wt + n * Kp + ks * 32 + q * 8);
    }
}

// Layers 0 and 1 (both write relu'd f16 into H buffers, stride 136).
// Transposed compute: D' = W^T * X^T. B-operand: lane j=(lane&15) -> data row m,
// k = q*8+j. Output D'[n][m]: n = q*4+reg (within n-tile), m = lane&15.
template <int NK0>
DI void l01(const f16x8 (*w0f)[4], const f16x8 (*w1f)[4],
            const _Float16* __restrict__ X, int xstride,
            _Float16* __restrict__ H0, _Float16* __restrict__ H1,
            int mrow, int nh, int q) {
    const f32x4 zero = {0.f, 0.f, 0.f, 0.f};
    f32x4 acc[4];
#pragma unroll
    for (int nt = 0; nt < 4; ++nt) acc[nt] = zero;
#pragma unroll
    for (int ks = 0; ks < NK0; ++ks) {
        f16x8 x = *(const f16x8*)(X + mrow * xstride + ks * 32 + q * 8);
#pragma unroll
        for (int nt = 0; nt < 4; ++nt) acc[nt] = mfma16(w0f[ks][nt], x, acc[nt]);
    }
#pragma unroll
    for (int nt = 0; nt < 4; ++nt) {
        f16x4 h;
#pragma unroll
        for (int i = 0; i < 4; ++i) h[i] = (_Float16)fmaxf(acc[nt][i], 0.f);
        *(f16x4*)(H0 + mrow * 136 + nh * 64 + nt * 16 + q * 4) = h;
    }
    __syncthreads();
    f32x4 a1[4];
#pragma unroll
    for (int nt = 0; nt < 4; ++nt) a1[nt] = zero;
#pragma unroll
    for (int ks = 0; ks < 4; ++ks) {
        f16x8 x = *(const f16x8*)(H0 + mrow * 136 + ks * 32 + q * 8);
#pragma unroll
        for (int nt = 0; nt < 4; ++nt) a1[nt] = mfma16(w1f[ks][nt], x, a1[nt]);
    }
#pragma unroll
    for (int nt = 0; nt < 4; ++nt) {
        f16x4 h;
#pragma unroll
        for (int i = 0; i < 4; ++i) h[i] = (_Float16)fmaxf(a1[nt][i], 0.f);
        *(f16x4*)(H1 + mrow * 136 + nh * 64 + nt * 16 + q * 4) = h;
    }
    __syncthreads();
}

DI f32x4 l2(const f16x8* w2f, const _Float16* __restrict__ H1, int mrow, int q) {
    f32x4 acc = {0.f, 0.f, 0.f, 0.f};
#pragma unroll
    for (int ks = 0; ks < 4; ++ks) {
        f16x8 x = *(const f16x8*)(H1 + mrow * 136 + ks * 32 + q * 8);
        acc = mfma16(w2f[ks], x, acc);
    }
    return acc;
}

// ---------------- weight prep: fp32 [K][N] -> f16 W^T [Np][Kp] (zero padded) ----
struct WPtrs { const float* p[15]; };

__global__ void k_prep(WPtrs wp, _Float16* __restrict__ ws) {
    int b = blockIdx.x;
    const float* src; int K, N, Np, Kp, off;
    if (b == 0)       { src = wp.p[0];  K = 3;   N = 128; Np = 128; Kp = 32;  off = 0; }
    else if (b == 1)  { src = wp.p[1];  K = 128; N = 128; Np = 128; Kp = 128; off = 4096; }
    else if (b == 2)  { src = wp.p[2];  K = 128; N = 32;  Np = 32;  Kp = 128; off = 20480; }
    else if (b == 3)  { src = wp.p[3];  K = 3;   N = 128; Np = 128; Kp = 32;  off = 24576; }
    else if (b == 4)  { src = wp.p[4];  K = 128; N = 128; Np = 128; Kp = 128; off = 28672; }
    else if (b == 5)  { src = wp.p[5];  K = 128; N = 32;  Np = 32;  Kp = 128; off = 45056; }
    else if (b <= 9)  { int t = b - 6;  src = wp.p[6] + t * 12288;  K = 96;  N = 128; Np = 128; Kp = 96;  off = 49152 + t * 32768; }
    else if (b <= 13) { int t = b - 10; src = wp.p[7] + t * 16384;  K = 128; N = 128; Np = 128; Kp = 128; off = 61440 + t * 32768; }
    else if (b <= 17) { int t = b - 14; src = wp.p[8] + t * 4096;   K = 128; N = 32;  Np = 32;  Kp = 128; off = 77824 + t * 32768; }
    else if (b <= 21) { int t = b - 18; src = wp.p[9] + t * 8192;   K = 64;  N = 128; Np = 128; Kp = 64;  off = 180224 + t * 28672; }
    else if (b <= 25) { int t = b - 22; src = wp.p[10] + t * 16384; K = 128; N = 128; Np = 128; Kp = 128; off = 188416 + t * 28672; }
    else if (b <= 29) { int t = b - 26; src = wp.p[11] + t * 4096;  K = 128; N = 32;  Np = 32;  Kp = 128; off = 204800 + t * 28672; }
    else if (b == 30) { src = wp.p[12]; K = 32;  N = 128; Np = 128; Kp = 32;  off = 294912; }
    else if (b == 31) { src = wp.p[13]; K = 128; N = 128; Np = 128; Kp = 128; off = 299008; }
    else              { src = wp.p[14]; K = 128; N = 1;   Np = 16;  Kp = 128; off = 315392; }
    int total = Np * Kp;
    for (int i = threadIdx.x; i < total; i += 256) {
        int n = i / Kp, k = i - n * Kp;
        float v = (k < K && n < N) ? src[k * N + n] : 0.f;
        ws[off + i] = (_Float16)v;
    }
}

// ---------------- encoder: fp32 [M][3] -> MLP(32p->128->128->32) -> fp32 out ------
__global__ __launch_bounds__(256, 5) void k_enc(
    const float* __restrict__ in, float* __restrict__ out,
    const _Float16* __restrict__ w0t, const _Float16* __restrict__ w1t,
    const _Float16* __restrict__ w2t, int ntiles) {
    __shared__ __align__(16) _Float16 Xp[32 * 40];
    __shared__ __align__(16) _Float16 H0[32 * 136];
    __shared__ __align__(16) _Float16 H1[32 * 136];
    const int tid = threadIdx.x, wave = tid >> 6, lane = tid & 63;
    const int q = lane >> 4, l16 = lane & 15;
    const int mt = wave & 1, nh = wave >> 1;
    const int mrow = mt * 16 + l16;
    f16x8 w0f[1][4], w1f[4][4], w2f[4];
    load_wf4<1>(w0t, 32, nh * 64, l16, q, w0f);
    load_wf4<4>(w1t, 128, nh * 64, l16, q, w1f);
    {
        int n2 = nh * 16 + l16;
#pragma unroll
        for (int ks = 0; ks < 4; ++ks)
            w2f[ks] = *(const f16x8*)(w2t + n2 * 128 + ks * 32 + q * 8);
    }
    for (int tile = blockIdx.x; tile < ntiles; tile += gridDim.x) {
        int m0 = tile * 32;
        for (int c = tid; c < 1024; c += 256) {
            int r = c >> 5, cc = c & 31;
            float v = (cc < 3) ? in[(m0 + r) * 3 + cc] : 0.f;
            Xp[r * 40 + cc] = (_Float16)v;
        }
        __syncthreads();
        l01<1>(w0f, w1f, Xp, 40, H0, H1, mrow, nh, q);
        f32x4 o = l2(w2f, H1, mrow, q);
        int col = nh * 16 + q * 4;
        *(f32x4*)(out + (m0 + mrow) * 32 + col) = o;
        __syncthreads();
    }
}

// ---------------- edge update: [edge|node_s|node_r](96) -> MLP -> +res, atomic agg -
// node/edge persistent latents are fp32; f16 only at the MFMA staging boundary.
__global__ __launch_bounds__(256, 5) void k_edge(
    const float* __restrict__ node, float* __restrict__ edge,
    const int* __restrict__ gi,
    const _Float16* __restrict__ w0t, const _Float16* __restrict__ w1t,
    const _Float16* __restrict__ w2t, float* __restrict__ agg) {
    __shared__ __align__(16) _Float16 Xe[32 * 104];
    __shared__ __align__(16) _Float16 H0[32 * 136];
    __shared__ __align__(16) _Float16 H1[32 * 136];
    const int tid = threadIdx.x, wave = tid >> 6, lane = tid & 63;
    const int q = lane >> 4, l16 = lane & 15;
    const int mt = wave & 1, nh = wave >> 1;
    const int mrow = mt * 16 + l16;
    f16x8 w0f[3][4], w1f[4][4], w2f[4];
    load_wf4<3>(w0t, 96, nh * 64, l16, q, w0f);
    load_wf4<4>(w1t, 128, nh * 64, l16, q, w1f);
    {
        int n2 = nh * 16 + l16;
#pragma unroll
        for (int ks = 0; ks < 4; ++ks)
            w2f[ks] = *(const f16x8*)(w2t + n2 * 128 + ks * 32 + q * 8);
    }
    for (int tile = blockIdx.x; tile < 16000; tile += gridDim.x) {
        int e0 = tile * 32;
        // stage 96 fp32 -> f16 per row; 24 float4-chunks per row
        for (int c = tid; c < 768; c += 256) {
            int r = c / 24, s = c - r * 24;
            int e = e0 + r;
            const float* src;
            if (s < 8) src = edge + e * 32 + s * 4;
            else if (s < 16) src = node + gi[2 * e] * 32 + (s - 8) * 4;
            else src = node + gi[2 * e + 1] * 32 + (s - 16) * 4;
            f32x4 v = *(const f32x4*)src;
            f16x4 h;
#pragma unroll
            for (int i = 0; i < 4; ++i) h[i] = (_Float16)v[i];
            *(f16x4*)(Xe + r * 104 + s * 4) = h;
        }
        __syncthreads();
        l01<3>(w0f, w1f, Xe, 104, H0, H1, mrow, nh, q);
        f32x4 o = l2(w2f, H1, mrow, q);
        int e = e0 + mrow;
        int col = nh * 16 + q * 4;
        f32x4 old = *(const f32x4*)(edge + e * 32 + col);
        f32x4 nv;
#pragma unroll
        for (int i = 0; i < 4; ++i) nv[i] = o[i] + old[i];
        *(f32x4*)(edge + e * 32 + col) = nv;
        int rcv = gi[2 * e + 1];
        float* ap = agg + rcv * 32 + col;
#pragma unroll
        for (int i = 0; i < 4; ++i) unsafeAtomicAdd(ap + i, nv[i]);
        __syncthreads();
    }
}

// ---------------- node update: [node|agg](64) -> MLP -> +res -> node --------------
__global__ __launch_bounds__(256, 5) void k_node(
    float* __restrict__ node, const float* __restrict__ agg,
    const _Float16* __restrict__ w0t, const _Float16* __restrict__ w1t,
    const _Float16* __restrict__ w2t) {
    __shared__ __align__(16) _Float16 Xn[32 * 72];
    __shared__ __align__(16) _Float16 H0[32 * 136];
    __shared__ __align__(16) _Float16 H1[32 * 136];
    const int tid = threadIdx.x, wave = tid >> 6, lane = tid & 63;
    const int q = lane >> 4, l16 = lane & 15;
    const int mt = wave & 1, nh = wave >> 1;
    const int mrow = mt * 16 + l16;
    f16x8 w0f[2][4], w1f[4][4], w2f[4];
    load_wf4<2>(w0t, 64, nh * 64, l16, q, w0f);
    load_wf4<4>(w1t, 128, nh * 64, l16, q, w1f);
    {
        int n2 = nh * 16 + l16;
#pragma unroll
        for (int ks = 0; ks < 4; ++ks)
            w2f[ks] = *(const f16x8*)(w2t + n2 * 128 + ks * 32 + q * 8);
    }
    for (int tile = blockIdx.x; tile < 1000; tile += gridDim.x) {
        int n0 = tile * 32;
        // 16 float4 chunks per row: s<8 node, s>=8 agg
        for (int c = tid; c < 512; c += 256) {
            int r = c >> 4, s = c & 15;
            const float* src = (s < 8) ? (node + (n0 + r) * 32 + s * 4)
                                       : (agg + (n0 + r) * 32 + (s - 8) * 4);
            f32x4 v = *(const f32x4*)src;
            f16x4 h;
#pragma unroll
            for (int i = 0; i < 4; ++i) h[i] = (_Float16)v[i];
            *(f16x4*)(Xn + r * 72 + s * 4) = h;
        }
        __syncthreads();
        l01<2>(w0f, w1f, Xn, 72, H0, H1, mrow, nh, q);
        f32x4 o = l2(w2f, H1, mrow, q);
        int col = nh * 16 + q * 4;
        f32x4 old = *(const f32x4*)(node + (n0 + mrow) * 32 + col);
        f32x4 nv;
#pragma unroll
        for (int i = 0; i < 4; ++i) nv[i] = o[i] + old[i];
        *(f32x4*)(node + (n0 + mrow) * 32 + col) = nv;
        __syncthreads();
    }
}

// ---------------- decoder: node(32) -> MLP(32->128->128->1) -> fp32 out ----------
__global__ __launch_bounds__(256, 5) void k_dec(
    const float* __restrict__ node,
    const _Float16* __restrict__ w0t, const _Float16* __restrict__ w1t,
    const _Float16* __restrict__ w2t, float* __restrict__ out) {
    __shared__ __align__(16) _Float16 Xd[32 * 40];
    __shared__ __align__(16) _Float16 H0[32 * 136];
    __shared__ __align__(16) _Float16 H1[32 * 136];
    const int tid = threadIdx.x, wave = tid >> 6, lane = tid & 63;
    const int q = lane >> 4, l16 = lane & 15;
    const int mt = wave & 1, nh = wave >> 1;
    const int mrow = mt * 16 + l16;
    f16x8 w0f[1][4], w1f[4][4], w2f[4];
    load_wf4<1>(w0t, 32, nh * 64, l16, q, w0f);
    load_wf4<4>(w1t, 128, nh * 64, l16, q, w1f);
    {
        int n2 = l16;  // padded W2^T is [16][128]; all waves load tile 0
#pragma unroll
        for (int ks = 0; ks < 4; ++ks)
            w2f[ks] = *(const f16x8*)(w2t + n2 * 128 + ks * 32 + q * 8);
    }
    for (int tile = blockIdx.x; tile < 1000; tile += gridDim.x) {
        int m0 = tile * 32;
        for (int c = tid; c < 256; c += 256) {
            int r = c >> 3, s = c & 7;
            f32x4 v = *(const f32x4*)(node + (m0 + r) * 32 + s * 4);
            f16x4 h;
#pragma unroll
            for (int i = 0; i < 4; ++i) h[i] = (_Float16)v[i];
            *(f16x4*)(Xd + r * 40 + s * 4) = h;
        }
        __syncthreads();
        l01<1>(w0f, w1f, Xd, 40, H0, H1, mrow, nh, q);
        if (nh == 0) {
            f32x4 o = l2(w2f, H1, mrow, q);
            if (q == 0) out[m0 + mrow] = o[0];  // feature n=0 lives in reg 0 of quad 0
        }
        __syncthreads();
    }
}

extern "C" void kernel_launch(void* const* d_in, const int* in_sizes, int n_in,
                              void* d_out, int out_size, void* d_ws, size_t ws_size,
                              hipStream_t stream) {
    const float* input_node = (const float*)d_in[0];
    const float* input_edge = (const float*)d_in[1];
    const int* gi = (const int*)d_in[2];

    _Float16* ws = (_Float16*)d_ws;
    // ws layout (bytes):
    //   weights f16:         [0, 634,880)
    //   node fp32 32000x32:  [655,360, 4,751,360)
    //   edge fp32 512000x32: [4,751,360, 70,287,360)
    //   agg fp32 32000x32:   [70,287,360, 74,383,360)
    float* node = (float*)((char*)d_ws + 655360);
    float* edge = (float*)((char*)d_ws + 4751360);
    float* agg  = (float*)((char*)d_ws + 70287360);

    WPtrs wp;
    for (int i = 0; i < 15; ++i) wp.p[i] = (const float*)d_in[3 + i];

    k_prep<<<33, 256, 0, stream>>>(wp, ws);

    k_enc<<<1000, 256, 0, stream>>>(input_node, node, ws + 0, ws + 4096, ws + 20480, 1000);
    k_enc<<<1280, 256, 0, stream>>>(input_edge, edge, ws + 24576, ws + 28672, ws + 45056, 16000);

    for (int t = 0; t < 4; ++t) {
        hipMemsetAsync(agg, 0, 32000 * 32 * sizeof(float), stream);
        k_edge<<<1280, 256, 0, stream>>>(node, edge, gi,
                                         ws + 49152 + t * 32768,
                                         ws + 61440 + t * 32768,
                                         ws + 77824 + t * 32768, agg);
        k_node<<<1000, 256, 0, stream>>>(node, agg,
                                         ws + 180224 + t * 28672,
                                         ws + 188416 + t * 28672,
                                         ws + 204800 + t * 28672);
    }
    k_dec<<<1000, 256, 0, stream>>>(node, ws + 294912, ws + 299008, ws + 315392,
                                    (float*)d_out);
}

// Round 5
// 1133.118 us; speedup vs baseline: 1.4340x; 1.4340x over previous
//
#include <hip/hip_runtime.h>

typedef __attribute__((ext_vector_type(8))) _Float16 f16x8;
typedef __attribute__((ext_vector_type(4))) _Float16 f16x4;
typedef __attribute__((ext_vector_type(4))) float f32x4;

#define DI __device__ __forceinline__
// Raw barrier: LDS-drain only (lgkmcnt). Avoids the compiler's vmcnt(0) drain
// that would serialize in-flight register prefetches across the barrier.
#define BAR() asm volatile("s_waitcnt lgkmcnt(0)\n\ts_barrier" ::: "memory")

DI f32x4 mfma16(f16x8 a, f16x8 b, f32x4 c) {
    return __builtin_amdgcn_mfma_f32_16x16x32_f16(a, b, c, 0, 0, 0);
}

// Load weight fragments for 4 n-tiles x NK k-steps. wt is W^T [N][Kp] f16 row-major.
// A-operand layout: lane i=(lane&15) holds row n, k = q*8 + j (j=0..7), plus ks*32.
template <int NK>
DI void load_wf4(const _Float16* __restrict__ wt, int Kp, int nbase, int l16, int q,
                 f16x8 f[NK][4]) {
#pragma unroll
    for (int nt = 0; nt < 4; ++nt) {
        int n = nbase + nt * 16 + l16;
#pragma unroll
        for (int ks = 0; ks < NK; ++ks)
            f[ks][nt] = *(const f16x8*)(wt + n * Kp + ks * 32 + q * 8);
    }
}

// Layers 0 and 1 (both write relu'd f16 into H buffers, stride 136).
// Transposed compute: D' = W^T * X^T. B-operand: lane j=(lane&15) -> data row m,
// k = q*8+j. Output D'[n][m]: n = q*4+reg (within n-tile), m = lane&15.
template <int NK0>
DI void l01(const f16x8 (*w0f)[4], const f16x8 (*w1f)[4],
            const _Float16* __restrict__ X, int xstride,
            _Float16* __restrict__ H0, _Float16* __restrict__ H1,
            int mrow, int nh, int q) {
    const f32x4 zero = {0.f, 0.f, 0.f, 0.f};
    f32x4 acc[4];
#pragma unroll
    for (int nt = 0; nt < 4; ++nt) acc[nt] = zero;
#pragma unroll
    for (int ks = 0; ks < NK0; ++ks) {
        f16x8 x = *(const f16x8*)(X + mrow * xstride + ks * 32 + q * 8);
#pragma unroll
        for (int nt = 0; nt < 4; ++nt) acc[nt] = mfma16(w0f[ks][nt], x, acc[nt]);
    }
#pragma unroll
    for (int nt = 0; nt < 4; ++nt) {
        f16x4 h;
#pragma unroll
        for (int i = 0; i < 4; ++i) h[i] = (_Float16)fmaxf(acc[nt][i], 0.f);
        *(f16x4*)(H0 + mrow * 136 + nh * 64 + nt * 16 + q * 4) = h;
    }
    BAR();
    f32x4 a1[4];
#pragma unroll
    for (int nt = 0; nt < 4; ++nt) a1[nt] = zero;
#pragma unroll
    for (int ks = 0; ks < 4; ++ks) {
        f16x8 x = *(const f16x8*)(H0 + mrow * 136 + ks * 32 + q * 8);
#pragma unroll
        for (int nt = 0; nt < 4; ++nt) a1[nt] = mfma16(w1f[ks][nt], x, a1[nt]);
    }
#pragma unroll
    for (int nt = 0; nt < 4; ++nt) {
        f16x4 h;
#pragma unroll
        for (int i = 0; i < 4; ++i) h[i] = (_Float16)fmaxf(a1[nt][i], 0.f);
        *(f16x4*)(H1 + mrow * 136 + nh * 64 + nt * 16 + q * 4) = h;
    }
    BAR();
}

DI f32x4 l2(const f16x8* w2f, const _Float16* __restrict__ H1, int mrow, int q) {
    f32x4 acc = {0.f, 0.f, 0.f, 0.f};
#pragma unroll
    for (int ks = 0; ks < 4; ++ks) {
        f16x8 x = *(const f16x8*)(H1 + mrow * 136 + ks * 32 + q * 8);
        acc = mfma16(w2f[ks], x, acc);
    }
    return acc;
}

// ---------------- weight prep: fp32 [K][N] -> f16 W^T [Np][Kp] (zero padded) ----
struct WPtrs { const float* p[15]; };

__global__ void k_prep(WPtrs wp, _Float16* __restrict__ ws) {
    int b = blockIdx.x;
    const float* src; int K, N, Np, Kp, off;
    if (b == 0)       { src = wp.p[0];  K = 3;   N = 128; Np = 128; Kp = 32;  off = 0; }
    else if (b == 1)  { src = wp.p[1];  K = 128; N = 128; Np = 128; Kp = 128; off = 4096; }
    else if (b == 2)  { src = wp.p[2];  K = 128; N = 32;  Np = 32;  Kp = 128; off = 20480; }
    else if (b == 3)  { src = wp.p[3];  K = 3;   N = 128; Np = 128; Kp = 32;  off = 24576; }
    else if (b == 4)  { src = wp.p[4];  K = 128; N = 128; Np = 128; Kp = 128; off = 28672; }
    else if (b == 5)  { src = wp.p[5];  K = 128; N = 32;  Np = 32;  Kp = 128; off = 45056; }
    else if (b <= 9)  { int t = b - 6;  src = wp.p[6] + t * 12288;  K = 96;  N = 128; Np = 128; Kp = 96;  off = 49152 + t * 32768; }
    else if (b <= 13) { int t = b - 10; src = wp.p[7] + t * 16384;  K = 128; N = 128; Np = 128; Kp = 128; off = 61440 + t * 32768; }
    else if (b <= 17) { int t = b - 14; src = wp.p[8] + t * 4096;   K = 128; N = 32;  Np = 32;  Kp = 128; off = 77824 + t * 32768; }
    else if (b <= 21) { int t = b - 18; src = wp.p[9] + t * 8192;   K = 64;  N = 128; Np = 128; Kp = 64;  off = 180224 + t * 28672; }
    else if (b <= 25) { int t = b - 22; src = wp.p[10] + t * 16384; K = 128; N = 128; Np = 128; Kp = 128; off = 188416 + t * 28672; }
    else if (b <= 29) { int t = b - 26; src = wp.p[11] + t * 4096;  K = 128; N = 32;  Np = 32;  Kp = 128; off = 204800 + t * 28672; }
    else if (b == 30) { src = wp.p[12]; K = 32;  N = 128; Np = 128; Kp = 32;  off = 294912; }
    else if (b == 31) { src = wp.p[13]; K = 128; N = 128; Np = 128; Kp = 128; off = 299008; }
    else              { src = wp.p[14]; K = 128; N = 1;   Np = 16;  Kp = 128; off = 315392; }
    int total = Np * Kp;
    for (int i = threadIdx.x; i < total; i += 256) {
        int n = i / Kp, k = i - n * Kp;
        float v = (k < K && n < N) ? src[k * N + n] : 0.f;
        ws[off + i] = (_Float16)v;
    }
}

// ---------------- encoder: fp32 [M][3] -> MLP(32p->128->128->32) -> fp32 out ------
// aggz != nullptr (node path): also zero the agg rows for this tile.
__global__ __launch_bounds__(256, 2) void k_enc(
    const float* __restrict__ in, float* __restrict__ out,
    const _Float16* __restrict__ w0t, const _Float16* __restrict__ w1t,
    const _Float16* __restrict__ w2t, int NT, float* __restrict__ aggz) {
    __shared__ __align__(16) _Float16 Xp[32 * 40];
    __shared__ __align__(16) _Float16 H0[32 * 136];
    __shared__ __align__(16) _Float16 H1[32 * 136];
    const int tid = threadIdx.x, wave = tid >> 6, lane = tid & 63;
    const int q = lane >> 4, l16 = lane & 15;
    const int mt = wave & 1, nh = wave >> 1;
    const int mrow = mt * 16 + l16;
    const int col = nh * 16 + q * 4;
    f16x8 w0f[1][4], w1f[4][4], w2f[4];
    load_wf4<1>(w0t, 32, nh * 64, l16, q, w0f);
    load_wf4<4>(w1t, 128, nh * 64, l16, q, w1f);
    {
        int n2 = nh * 16 + l16;
#pragma unroll
        for (int ks = 0; ks < 4; ++ks)
            w2f[ks] = *(const f16x8*)(w2t + n2 * 128 + ks * 32 + q * 8);
    }
    // zero-fill all of Xp once; per-tile staging only rewrites cc<3.
    for (int c = tid; c < 1280; c += 256) Xp[c] = (_Float16)0.f;
    BAR();

    const int g = gridDim.x;
    const int dr = tid / 3, dc = tid - dr * 3;  // valid when tid<96
    int t = blockIdx.x;
    int tn = t + g; if (tn >= NT) tn = t;
    float v = (tid < 96) ? in[t * 96 + tid] : 0.f;

    while (true) {
        if (tid < 96) Xp[dr * 40 + dc] = (_Float16)v;
        BAR();
        float vn = (tid < 96) ? in[tn * 96 + tid] : 0.f;
        if (aggz) {
            const f32x4 z4 = {0.f, 0.f, 0.f, 0.f};
            int rr = tid >> 3, ss = tid & 7;
            *(f32x4*)(aggz + (t * 32 + rr) * 32 + ss * 4) = z4;
        }
        l01<1>(w0f, w1f, Xp, 40, H0, H1, mrow, nh, q);
        f32x4 o = l2(w2f, H1, mrow, q);
        *(f32x4*)(out + (t * 32 + mrow) * 32 + col) = o;
        if (tn == t) break;
        t = tn; tn = t + g; if (tn >= NT) tn = t;
        v = vn;
    }
}

// ---------------- edge update: [edge|node_s|node_r](96) -> MLP -> +res, atomic agg -
// Software-pipelined: gi two tiles ahead, gathers/old one tile ahead, raw barriers.
__global__ __launch_bounds__(256, 2) void k_edge(
    const float* __restrict__ node, float* __restrict__ edge,
    const int* __restrict__ gi,
    const _Float16* __restrict__ w0t, const _Float16* __restrict__ w1t,
    const _Float16* __restrict__ w2t, float* __restrict__ agg) {
    __shared__ __align__(16) _Float16 Xe[32 * 104];
    __shared__ __align__(16) _Float16 H0[32 * 136];
    __shared__ __align__(16) _Float16 H1[32 * 136];
    const int tid = threadIdx.x, wave = tid >> 6, lane = tid & 63;
    const int q = lane >> 4, l16 = lane & 15;
    const int mt = wave & 1, nh = wave >> 1;
    const int mrow = mt * 16 + l16;
    const int col = nh * 16 + q * 4;
    f16x8 w0f[3][4], w1f[4][4], w2f[4];
    load_wf4<3>(w0t, 96, nh * 64, l16, q, w0f);
    load_wf4<4>(w1t, 128, nh * 64, l16, q, w1f);
    {
        int n2 = nh * 16 + l16;
#pragma unroll
        for (int ks = 0; ks < 4; ++ks)
            w2f[ks] = *(const f16x8*)(w2t + n2 * 128 + ks * 32 + q * 8);
    }
    int cr[3], cs[3];
#pragma unroll
    for (int j = 0; j < 3; ++j) { int c = tid + 256 * j; cr[j] = c / 24; cs[j] = c - cr[j] * 24; }

    const int NT = 16000, g = gridDim.x;
    int t = blockIdx.x;
    int tn = t + g; if (tn >= NT) tn = t;

    // prologue: tile t fully loaded, gi for tile tn in flight
    int2 ngn[3]; f32x4 v[3]; f32x4 oldv; int rcv;
    {
        int2 ng0[3];
#pragma unroll
        for (int j = 0; j < 3; ++j) ng0[j] = *(const int2*)(gi + 2 * (t * 32 + cr[j]));
#pragma unroll
        for (int j = 0; j < 3; ++j) {
            int e = t * 32 + cr[j], s = cs[j];
            const float* src = (s < 8) ? edge + e * 32 + s * 4
                             : (s < 16) ? node + ng0[j].x * 32 + (s - 8) * 4
                                        : node + ng0[j].y * 32 + (s - 16) * 4;
            v[j] = *(const f32x4*)src;
        }
        oldv = *(const f32x4*)(edge + (t * 32 + mrow) * 32 + col);
        rcv = gi[2 * (t * 32 + mrow) + 1];
#pragma unroll
        for (int j = 0; j < 3; ++j) ngn[j] = *(const int2*)(gi + 2 * (tn * 32 + cr[j]));
    }

    while (true) {
        // stage tile t into LDS
#pragma unroll
        for (int j = 0; j < 3; ++j) {
            f16x4 h;
#pragma unroll
            for (int i = 0; i < 4; ++i) h[i] = (_Float16)v[j][i];
            *(f16x4*)(Xe + cr[j] * 104 + cs[j] * 4) = h;
        }
        BAR();
        // prefetch tile tn (data, old, rcv) and gi for tile tn2 — overlaps MLP below
        int tn2 = tn + g; if (tn2 >= NT) tn2 = tn;
        f32x4 vn[3], oldn; int rcvn; int2 ng2[3];
#pragma unroll
        for (int j = 0; j < 3; ++j) {
            int e = tn * 32 + cr[j], s = cs[j];
            const float* src = (s < 8) ? edge + e * 32 + s * 4
                             : (s < 16) ? node + ngn[j].x * 32 + (s - 8) * 4
                                        : node + ngn[j].y * 32 + (s - 16) * 4;
            vn[j] = *(const f32x4*)src;
        }
        oldn = *(const f32x4*)(edge + (tn * 32 + mrow) * 32 + col);
        rcvn = gi[2 * (tn * 32 + mrow) + 1];
#pragma unroll
        for (int j = 0; j < 3; ++j) ng2[j] = *(const int2*)(gi + 2 * (tn2 * 32 + cr[j]));

        l01<3>(w0f, w1f, Xe, 104, H0, H1, mrow, nh, q);
        f32x4 o = l2(w2f, H1, mrow, q);
        // epilogue for tile t
        int e = t * 32 + mrow;
        f32x4 nv;
#pragma unroll
        for (int i = 0; i < 4; ++i) nv[i] = o[i] + oldv[i];
        *(f32x4*)(edge + e * 32 + col) = nv;
        float* ap = agg + rcv * 32 + col;
#pragma unroll
        for (int i = 0; i < 4; ++i) unsafeAtomicAdd(ap + i, nv[i]);

        if (tn == t) break;
        t = tn; tn = tn2;
#pragma unroll
        for (int j = 0; j < 3; ++j) { v[j] = vn[j]; ngn[j] = ng2[j]; }
        oldv = oldn; rcv = rcvn;
    }
}

// ---------------- node update: [node|agg](64) -> MLP -> +res -> node --------------
// Pipelined like k_edge; zeroes agg rows after staging them (replaces memset).
__global__ __launch_bounds__(256, 2) void k_node(
    float* __restrict__ node, float* __restrict__ agg,
    const _Float16* __restrict__ w0t, const _Float16* __restrict__ w1t,
    const _Float16* __restrict__ w2t) {
    __shared__ __align__(16) _Float16 Xn[32 * 72];
    __shared__ __align__(16) _Float16 H0[32 * 136];
    __shared__ __align__(16) _Float16 H1[32 * 136];
    const int tid = threadIdx.x, wave = tid >> 6, lane = tid & 63;
    const int q = lane >> 4, l16 = lane & 15;
    const int mt = wave & 1, nh = wave >> 1;
    const int mrow = mt * 16 + l16;
    const int col = nh * 16 + q * 4;
    f16x8 w0f[2][4], w1f[4][4], w2f[4];
    load_wf4<2>(w0t, 64, nh * 64, l16, q, w0f);
    load_wf4<4>(w1t, 128, nh * 64, l16, q, w1f);
    {
        int n2 = nh * 16 + l16;
#pragma unroll
        for (int ks = 0; ks < 4; ++ks)
            w2f[ks] = *(const f16x8*)(w2t + n2 * 128 + ks * 32 + q * 8);
    }
    int cr[2], cs[2];
#pragma unroll
    for (int j = 0; j < 2; ++j) { int c = tid + 256 * j; cr[j] = c >> 4; cs[j] = c & 15; }

    const int NT = 1000, g = gridDim.x;
    int t = blockIdx.x;
    int tn = t + g; if (tn >= NT) tn = t;

    f32x4 v[2], oldv;
#pragma unroll
    for (int j = 0; j < 2; ++j) {
        int r = t * 32 + cr[j], s = cs[j];
        const float* src = (s < 8) ? node + r * 32 + s * 4 : agg + r * 32 + (s - 8) * 4;
        v[j] = *(const f32x4*)src;
    }
    oldv = *(const f32x4*)(node + (t * 32 + mrow) * 32 + col);

    const f32x4 z4 = {0.f, 0.f, 0.f, 0.f};
    while (true) {
#pragma unroll
        for (int j = 0; j < 2; ++j) {
            f16x4 h;
#pragma unroll
            for (int i = 0; i < 4; ++i) h[i] = (_Float16)v[j][i];
            *(f16x4*)(Xn + cr[j] * 72 + cs[j] * 4) = h;
        }
        BAR();
        // zero the agg rows we just consumed (ready for next k_edge pass)
#pragma unroll
        for (int j = 0; j < 2; ++j)
            if (cs[j] >= 8) *(f32x4*)(agg + (t * 32 + cr[j]) * 32 + (cs[j] - 8) * 4) = z4;
        // prefetch tile tn
        f32x4 vn[2], oldn;
#pragma unroll
        for (int j = 0; j < 2; ++j) {
            int r = tn * 32 + cr[j], s = cs[j];
            const float* src = (s < 8) ? node + r * 32 + s * 4 : agg + r * 32 + (s - 8) * 4;
            vn[j] = *(const f32x4*)src;
        }
        oldn = *(const f32x4*)(node + (tn * 32 + mrow) * 32 + col);

        l01<2>(w0f, w1f, Xn, 72, H0, H1, mrow, nh, q);
        f32x4 o = l2(w2f, H1, mrow, q);
        f32x4 nv;
#pragma unroll
        for (int i = 0; i < 4; ++i) nv[i] = o[i] + oldv[i];
        *(f32x4*)(node + (t * 32 + mrow) * 32 + col) = nv;

        if (tn == t) break;
        t = tn; tn = t + g; if (tn >= NT) tn = t;
        v[0] = vn[0]; v[1] = vn[1]; oldv = oldn;
    }
}

// ---------------- decoder: node(32) -> MLP(32->128->128->1) -> fp32 out ----------
__global__ __launch_bounds__(256, 2) void k_dec(
    const float* __restrict__ node,
    const _Float16* __restrict__ w0t, const _Float16* __restrict__ w1t,
    const _Float16* __restrict__ w2t, float* __restrict__ out) {
    __shared__ __align__(16) _Float16 Xd[32 * 40];
    __shared__ __align__(16) _Float16 H0[32 * 136];
    __shared__ __align__(16) _Float16 H1[32 * 136];
    const int tid = threadIdx.x, wave = tid >> 6, lane = tid & 63;
    const int q = lane >> 4, l16 = lane & 15;
    const int mt = wave & 1, nh = wave >> 1;
    const int mrow = mt * 16 + l16;
    f16x8 w0f[1][4], w1f[4][4], w2f[4];
    load_wf4<1>(w0t, 32, nh * 64, l16, q, w0f);
    load_wf4<4>(w1t, 128, nh * 64, l16, q, w1f);
    {
        int n2 = l16;  // padded W2^T is [16][128]; all waves load tile 0
#pragma unroll
        for (int ks = 0; ks < 4; ++ks)
            w2f[ks] = *(const f16x8*)(w2t + n2 * 128 + ks * 32 + q * 8);
    }
    const int cr = tid >> 3, cs = tid & 7;
    const int NT = 1000, g = gridDim.x;
    int t = blockIdx.x;
    int tn = t + g; if (tn >= NT) tn = t;
    f32x4 v = *(const f32x4*)(node + (t * 32 + cr) * 32 + cs * 4);

    while (true) {
        f16x4 h;
#pragma unroll
        for (int i = 0; i < 4; ++i) h[i] = (_Float16)v[i];
        *(f16x4*)(Xd + cr * 40 + cs * 4) = h;
        BAR();
        f32x4 vn = *(const f32x4*)(node + (tn * 32 + cr) * 32 + cs * 4);
        l01<1>(w0f, w1f, Xd, 40, H0, H1, mrow, nh, q);
        if (nh == 0) {
            f32x4 o = l2(w2f, H1, mrow, q);
            if (q == 0) out[t * 32 + mrow] = o[0];  // feature n=0: reg 0 of quad 0
        }
        if (tn == t) break;
        t = tn; tn = t + g; if (tn >= NT) tn = t;
        v = vn;
    }
}

extern "C" void kernel_launch(void* const* d_in, const int* in_sizes, int n_in,
                              void* d_out, int out_size, void* d_ws, size_t ws_size,
                              hipStream_t stream) {
    const float* input_node = (const float*)d_in[0];
    const float* input_edge = (const float*)d_in[1];
    const int* gi = (const int*)d_in[2];

    _Float16* ws = (_Float16*)d_ws;
    // ws layout (bytes):
    //   weights f16:         [0, 634,880)
    //   node fp32 32000x32:  [655,360, 4,751,360)
    //   edge fp32 512000x32: [4,751,360, 70,287,360)
    //   agg fp32 32000x32:   [70,287,360, 74,383,360)
    float* node = (float*)((char*)d_ws + 655360);
    float* edge = (float*)((char*)d_ws + 4751360);
    float* agg  = (float*)((char*)d_ws + 70287360);

    WPtrs wp;
    for (int i = 0; i < 15; ++i) wp.p[i] = (const float*)d_in[3 + i];

    k_prep<<<33, 256, 0, stream>>>(wp, ws);

    // node encode also zeroes agg (replaces first memset)
    k_enc<<<500, 256, 0, stream>>>(input_node, node, ws + 0, ws + 4096, ws + 20480,
                                   1000, agg);
    k_enc<<<512, 256, 0, stream>>>(input_edge, edge, ws + 24576, ws + 28672, ws + 45056,
                                   16000, nullptr);

    for (int t = 0; t < 4; ++t) {
        k_edge<<<512, 256, 0, stream>>>(node, edge, gi,
                                        ws + 49152 + t * 32768,
                                        ws + 61440 + t * 32768,
                                        ws + 77824 + t * 32768, agg);
        // k_node zeroes agg rows after reading them (replaces per-iter memset)
        k_node<<<500, 256, 0, stream>>>(node, agg,
                                        ws + 180224 + t * 28672,
                                        ws + 188416 + t * 28672,
                                        ws + 204800 + t * 28672);
    }
    k_dec<<<500, 256, 0, stream>>>(node, ws + 294912, ws + 299008, ws + 315392,
                                   (float*)d_out);
}

// Round 6
// 1027.934 us; speedup vs baseline: 1.5807x; 1.1023x over previous
//
#include <hip/hip_runtime.h>

typedef __attribute__((ext_vector_type(8))) _Float16 f16x8;
typedef __attribute__((ext_vector_type(4))) _Float16 f16x4;
typedef __attribute__((ext_vector_type(4))) float f32x4;

#define DI __device__ __forceinline__
// Raw barrier: LDS-drain only (lgkmcnt). Avoids the compiler's vmcnt(0) drain
// that would serialize in-flight register prefetches across the barrier.
#define BAR() asm volatile("s_waitcnt lgkmcnt(0)\n\ts_barrier" ::: "memory")

DI f32x4 mfma16(f16x8 a, f16x8 b, f32x4 c) {
    return __builtin_amdgcn_mfma_f32_16x16x32_f16(a, b, c, 0, 0, 0);
}

// Load weight fragments for 4 n-tiles x NK k-steps. wt is W^T [N][Kp] f16 row-major.
template <int NK>
DI void load_wf4(const _Float16* __restrict__ wt, int Kp, int nbase, int l16, int q,
                 f16x8 f[NK][4]) {
#pragma unroll
    for (int nt = 0; nt < 4; ++nt) {
        int n = nbase + nt * 16 + l16;
#pragma unroll
        for (int ks = 0; ks < NK; ++ks)
            f[ks][nt] = *(const f16x8*)(wt + n * Kp + ks * 32 + q * 8);
    }
}

// Layers 0/1: transposed compute D' = W^T X^T; relu'd f16 to H buffers (stride 136).
template <int NK0>
DI void l01(const f16x8 (*w0f)[4], const f16x8 (*w1f)[4],
            const _Float16* __restrict__ X, int xstride,
            _Float16* __restrict__ H0, _Float16* __restrict__ H1,
            int mrow, int nh, int q) {
    const f32x4 zero = {0.f, 0.f, 0.f, 0.f};
    f32x4 acc[4];
#pragma unroll
    for (int nt = 0; nt < 4; ++nt) acc[nt] = zero;
#pragma unroll
    for (int ks = 0; ks < NK0; ++ks) {
        f16x8 x = *(const f16x8*)(X + mrow * xstride + ks * 32 + q * 8);
#pragma unroll
        for (int nt = 0; nt < 4; ++nt) acc[nt] = mfma16(w0f[ks][nt], x, acc[nt]);
    }
#pragma unroll
    for (int nt = 0; nt < 4; ++nt) {
        f16x4 h;
#pragma unroll
        for (int i = 0; i < 4; ++i) h[i] = (_Float16)fmaxf(acc[nt][i], 0.f);
        *(f16x4*)(H0 + mrow * 136 + nh * 64 + nt * 16 + q * 4) = h;
    }
    BAR();
    f32x4 a1[4];
#pragma unroll
    for (int nt = 0; nt < 4; ++nt) a1[nt] = zero;
#pragma unroll
    for (int ks = 0; ks < 4; ++ks) {
        f16x8 x = *(const f16x8*)(H0 + mrow * 136 + ks * 32 + q * 8);
#pragma unroll
        for (int nt = 0; nt < 4; ++nt) a1[nt] = mfma16(w1f[ks][nt], x, a1[nt]);
    }
#pragma unroll
    for (int nt = 0; nt < 4; ++nt) {
        f16x4 h;
#pragma unroll
        for (int i = 0; i < 4; ++i) h[i] = (_Float16)fmaxf(a1[nt][i], 0.f);
        *(f16x4*)(H1 + mrow * 136 + nh * 64 + nt * 16 + q * 4) = h;
    }
    BAR();
}

DI f32x4 l2(const f16x8* w2f, const _Float16* __restrict__ H1, int mrow, int q) {
    f32x4 acc = {0.f, 0.f, 0.f, 0.f};
#pragma unroll
    for (int ks = 0; ks < 4; ++ks) {
        f16x8 x = *(const f16x8*)(H1 + mrow * 136 + ks * 32 + q * 8);
        acc = mfma16(w2f[ks], x, acc);
    }
    return acc;
}

// ---------------- weight prep: fp32 [K][N] -> f16 W^T [Np][Kp] (zero padded) ----
struct WPtrs { const float* p[15]; };

__global__ void k_prep(WPtrs wp, _Float16* __restrict__ ws) {
    int b = blockIdx.x;
    const float* src; int K, N, Np, Kp, off;
    if (b == 0)       { src = wp.p[0];  K = 3;   N = 128; Np = 128; Kp = 32;  off = 0; }
    else if (b == 1)  { src = wp.p[1];  K = 128; N = 128; Np = 128; Kp = 128; off = 4096; }
    else if (b == 2)  { src = wp.p[2];  K = 128; N = 32;  Np = 32;  Kp = 128; off = 20480; }
    else if (b == 3)  { src = wp.p[3];  K = 3;   N = 128; Np = 128; Kp = 32;  off = 24576; }
    else if (b == 4)  { src = wp.p[4];  K = 128; N = 128; Np = 128; Kp = 128; off = 28672; }
    else if (b == 5)  { src = wp.p[5];  K = 128; N = 32;  Np = 32;  Kp = 128; off = 45056; }
    else if (b <= 9)  { int t = b - 6;  src = wp.p[6] + t * 12288;  K = 96;  N = 128; Np = 128; Kp = 96;  off = 49152 + t * 32768; }
    else if (b <= 13) { int t = b - 10; src = wp.p[7] + t * 16384;  K = 128; N = 128; Np = 128; Kp = 128; off = 61440 + t * 32768; }
    else if (b <= 17) { int t = b - 14; src = wp.p[8] + t * 4096;   K = 128; N = 32;  Np = 32;  Kp = 128; off = 77824 + t * 32768; }
    else if (b <= 21) { int t = b - 18; src = wp.p[9] + t * 8192;   K = 64;  N = 128; Np = 128; Kp = 64;  off = 180224 + t * 28672; }
    else if (b <= 25) { int t = b - 22; src = wp.p[10] + t * 16384; K = 128; N = 128; Np = 128; Kp = 128; off = 188416 + t * 28672; }
    else if (b <= 29) { int t = b - 26; src = wp.p[11] + t * 4096;  K = 128; N = 32;  Np = 32;  Kp = 128; off = 204800 + t * 28672; }
    else if (b == 30) { src = wp.p[12]; K = 32;  N = 128; Np = 128; Kp = 32;  off = 294912; }
    else if (b == 31) { src = wp.p[13]; K = 128; N = 128; Np = 128; Kp = 128; off = 299008; }
    else              { src = wp.p[14]; K = 128; N = 1;   Np = 16;  Kp = 128; off = 315392; }
    int total = Np * Kp;
    for (int i = threadIdx.x; i < total; i += 256) {
        int n = i / Kp, k = i - n * Kp;
        float v = (k < K && n < N) ? src[k * N + n] : 0.f;
        ws[off + i] = (_Float16)v;
    }
}

// ---------------- CSR build: histogram -> scan -> scatter (u32 atomics only) -----
__global__ void k_zero(unsigned* __restrict__ p, int n) {
    int i = blockIdx.x * 256 + threadIdx.x;
    if (i < n) p[i] = 0u;
}
__global__ void k_hist(const int* __restrict__ gi, unsigned* __restrict__ cnt) {
    int e = blockIdx.x * 256 + threadIdx.x;
    if (e < 512000) atomicAdd(&cnt[gi[2 * e + 1]], 1u);
}
// one block, 1024 threads: exclusive scan of cnt[0..32000) -> rowptr, cursor
__global__ __launch_bounds__(1024) void k_scan(
    const unsigned* __restrict__ cnt, unsigned* __restrict__ rowptr,
    unsigned* __restrict__ cursor) {
    __shared__ unsigned s[1024];
    int t = threadIdx.x;
    unsigned loc[32];
    unsigned sum = 0;
#pragma unroll
    for (int i = 0; i < 32; ++i) {
        int idx = t * 32 + i;
        unsigned v = (idx < 32000) ? cnt[idx] : 0u;
        loc[i] = v; sum += v;
    }
    s[t] = sum;
    __syncthreads();
    if (t == 0) {
        unsigned run = 0;
        for (int i = 0; i < 1024; ++i) { unsigned tmp = s[i]; s[i] = run; run += tmp; }
        rowptr[32000] = run;
    }
    __syncthreads();
    unsigned off = s[t];
#pragma unroll
    for (int i = 0; i < 32; ++i) {
        int idx = t * 32 + i;
        if (idx < 32000) { rowptr[idx] = off; cursor[idx] = off; off += loc[i]; }
    }
}
__global__ void k_scatter(const int* __restrict__ gi, unsigned* __restrict__ cursor,
                          unsigned* __restrict__ iperm) {
    int e = blockIdx.x * 256 + threadIdx.x;
    if (e < 512000) {
        unsigned pos = atomicAdd(&cursor[gi[2 * e + 1]], 1u);
        iperm[pos] = (unsigned)e;
    }
}

// ---------------- encoder: fp32 [M][3] -> MLP -> fp32 out rows -------------------
// iperm != nullptr (edge path): row p of out corresponds to original edge iperm[p].
__global__ __launch_bounds__(256, 3) void k_enc(
    const float* __restrict__ in, float* __restrict__ out,
    const _Float16* __restrict__ w0t, const _Float16* __restrict__ w1t,
    const _Float16* __restrict__ w2t, int NT, const unsigned* __restrict__ iperm) {
    __shared__ __align__(16) _Float16 Xp[32 * 40];
    __shared__ __align__(16) _Float16 H0[32 * 136];
    __shared__ __align__(16) _Float16 H1[32 * 136];
    const int tid = threadIdx.x, wave = tid >> 6, lane = tid & 63;
    const int q = lane >> 4, l16 = lane & 15;
    const int mt = wave & 1, nh = wave >> 1;
    const int mrow = mt * 16 + l16;
    const int col = nh * 16 + q * 4;
    f16x8 w0f[1][4], w1f[4][4], w2f[4];
    load_wf4<1>(w0t, 32, nh * 64, l16, q, w0f);
    load_wf4<4>(w1t, 128, nh * 64, l16, q, w1f);
    {
        int n2 = nh * 16 + l16;
#pragma unroll
        for (int ks = 0; ks < 4; ++ks)
            w2f[ks] = *(const f16x8*)(w2t + n2 * 128 + ks * 32 + q * 8);
    }
    for (int c = tid; c < 1280; c += 256) Xp[c] = (_Float16)0.f;
    BAR();

    const int g = gridDim.x;
    const int dr = tid / 3, dc = tid - dr * 3;  // valid when tid<96
    int t = blockIdx.x;
    int tn = t + g; if (tn >= NT) tn = t;
    float v = 0.f;
    if (tid < 96) {
        unsigned e = iperm ? iperm[t * 32 + dr] : (unsigned)(t * 32 + dr);
        v = in[e * 3 + dc];
    }

    while (true) {
        if (tid < 96) Xp[dr * 40 + dc] = (_Float16)v;
        BAR();
        float vn = 0.f;
        if (tid < 96) {
            unsigned e = iperm ? iperm[tn * 32 + dr] : (unsigned)(tn * 32 + dr);
            vn = in[e * 3 + dc];
        }
        l01<1>(w0f, w1f, Xp, 40, H0, H1, mrow, nh, q);
        f32x4 o = l2(w2f, H1, mrow, q);
        *(f32x4*)(out + (t * 32 + mrow) * 32 + col) = o;
        if (tn == t) break;
        t = tn; tn = t + g; if (tn >= NT) tn = t;
        v = vn;
    }
}

// ---------------- edge update: [edge|node_s|node_r](96) -> MLP -> +res -----------
// Rows are receiver-sorted (edgeP). No atomics. Software-pipelined.
__global__ __launch_bounds__(256, 3) void k_edge(
    const float* __restrict__ node, float* __restrict__ edgeP,
    const int* __restrict__ gi, const unsigned* __restrict__ iperm,
    const _Float16* __restrict__ w0t, const _Float16* __restrict__ w1t,
    const _Float16* __restrict__ w2t) {
    __shared__ __align__(16) _Float16 Xe[32 * 104];
    __shared__ __align__(16) _Float16 H0[32 * 136];
    __shared__ __align__(16) _Float16 H1[32 * 136];
    const int tid = threadIdx.x, wave = tid >> 6, lane = tid & 63;
    const int q = lane >> 4, l16 = lane & 15;
    const int mt = wave & 1, nh = wave >> 1;
    const int mrow = mt * 16 + l16;
    const int col = nh * 16 + q * 4;
    f16x8 w0f[3][4], w1f[4][4], w2f[4];
    load_wf4<3>(w0t, 96, nh * 64, l16, q, w0f);
    load_wf4<4>(w1t, 128, nh * 64, l16, q, w1f);
    {
        int n2 = nh * 16 + l16;
#pragma unroll
        for (int ks = 0; ks < 4; ++ks)
            w2f[ks] = *(const f16x8*)(w2t + n2 * 128 + ks * 32 + q * 8);
    }
    int cr[3], cs[3];
#pragma unroll
    for (int j = 0; j < 3; ++j) { int c = tid + 256 * j; cr[j] = c / 24; cs[j] = c - cr[j] * 24; }

    const int NT = 16000, g = gridDim.x;
    int t = blockIdx.x;
    int tn = t + g; if (tn >= NT) tn = t;

    int2 ngn[3]; f32x4 v[3]; f32x4 oldv;
    {
        int2 ng0[3];
#pragma unroll
        for (int j = 0; j < 3; ++j) {
            unsigned ip = iperm[t * 32 + cr[j]];
            ng0[j] = *(const int2*)(gi + 2 * ip);
        }
#pragma unroll
        for (int j = 0; j < 3; ++j) {
            int p = t * 32 + cr[j], s = cs[j];
            const float* src = (s < 8) ? edgeP + p * 32 + s * 4
                             : (s < 16) ? node + ng0[j].x * 32 + (s - 8) * 4
                                        : node + ng0[j].y * 32 + (s - 16) * 4;
            v[j] = *(const f32x4*)src;
        }
        oldv = *(const f32x4*)(edgeP + (t * 32 + mrow) * 32 + col);
#pragma unroll
        for (int j = 0; j < 3; ++j) {
            unsigned ip = iperm[tn * 32 + cr[j]];
            ngn[j] = *(const int2*)(gi + 2 * ip);
        }
    }

    while (true) {
#pragma unroll
        for (int j = 0; j < 3; ++j) {
            f16x4 h;
#pragma unroll
            for (int i = 0; i < 4; ++i) h[i] = (_Float16)v[j][i];
            *(f16x4*)(Xe + cr[j] * 104 + cs[j] * 4) = h;
        }
        BAR();
        int tn2 = tn + g; if (tn2 >= NT) tn2 = tn;
        f32x4 vn[3], oldn; int2 ng2[3];
#pragma unroll
        for (int j = 0; j < 3; ++j) {
            int p = tn * 32 + cr[j], s = cs[j];
            const float* src = (s < 8) ? edgeP + p * 32 + s * 4
                             : (s < 16) ? node + ngn[j].x * 32 + (s - 8) * 4
                                        : node + ngn[j].y * 32 + (s - 16) * 4;
            vn[j] = *(const f32x4*)src;
        }
        oldn = *(const f32x4*)(edgeP + (tn * 32 + mrow) * 32 + col);
#pragma unroll
        for (int j = 0; j < 3; ++j) {
            unsigned ip = iperm[tn2 * 32 + cr[j]];
            ng2[j] = *(const int2*)(gi + 2 * ip);
        }

        l01<3>(w0f, w1f, Xe, 104, H0, H1, mrow, nh, q);
        f32x4 o = l2(w2f, H1, mrow, q);
        f32x4 nv;
#pragma unroll
        for (int i = 0; i < 4; ++i) nv[i] = o[i] + oldv[i];
        *(f32x4*)(edgeP + (t * 32 + mrow) * 32 + col) = nv;

        if (tn == t) break;
        t = tn; tn = tn2;
#pragma unroll
        for (int j = 0; j < 3; ++j) { v[j] = vn[j]; ngn[j] = ng2[j]; }
        oldv = oldn;
    }
}

// ---------------- node update: [node|csr_sum(edgeP)](64) -> MLP -> +res ----------
// One tile per block. Aggregation = contiguous segment sum (receiver-sorted rows).
__global__ __launch_bounds__(256, 3) void k_node(
    float* __restrict__ node, const float* __restrict__ edgeP,
    const unsigned* __restrict__ rowptr,
    const _Float16* __restrict__ w0t, const _Float16* __restrict__ w1t,
    const _Float16* __restrict__ w2t) {
    __shared__ __align__(16) _Float16 Xn[32 * 72];
    __shared__ __align__(16) _Float16 H0[32 * 136];
    __shared__ __align__(16) _Float16 H1[32 * 136];
    const int tid = threadIdx.x, wave = tid >> 6, lane = tid & 63;
    const int q = lane >> 4, l16 = lane & 15;
    const int mt = wave & 1, nh = wave >> 1;
    const int mrow = mt * 16 + l16;
    const int col = nh * 16 + q * 4;
    f16x8 w0f[2][4], w1f[4][4], w2f[4];
    load_wf4<2>(w0t, 64, nh * 64, l16, q, w0f);
    load_wf4<4>(w1t, 128, nh * 64, l16, q, w1f);
    {
        int n2 = nh * 16 + l16;
#pragma unroll
        for (int ks = 0; ks < 4; ++ks)
            w2f[ks] = *(const f16x8*)(w2t + n2 * 128 + ks * 32 + q * 8);
    }
    const int t = blockIdx.x;
    f32x4 oldv = *(const f32x4*)(node + (t * 32 + mrow) * 32 + col);
#pragma unroll
    for (int j = 0; j < 2; ++j) {
        int c = tid + 256 * j;
        int cr = c >> 4, cs = c & 15;
        int r = t * 32 + cr;
        f32x4 acc;
        if (cs < 8) {
            acc = *(const f32x4*)(node + r * 32 + cs * 4);
        } else {
            unsigned b = rowptr[r], e = rowptr[r + 1];
            const float* base = edgeP + (cs - 8) * 4;
            f32x4 a0 = {0.f,0.f,0.f,0.f}, a1 = a0, a2 = a0, a3 = a0;
            unsigned p = b;
            for (; p + 4 <= e; p += 4) {
                a0 += *(const f32x4*)(base + (p + 0) * 32);
                a1 += *(const f32x4*)(base + (p + 1) * 32);
                a2 += *(const f32x4*)(base + (p + 2) * 32);
                a3 += *(const f32x4*)(base + (p + 3) * 32);
            }
            for (; p < e; ++p) a0 += *(const f32x4*)(base + p * 32);
            acc = (a0 + a1) + (a2 + a3);
        }
        f16x4 h;
#pragma unroll
        for (int i = 0; i < 4; ++i) h[i] = (_Float16)acc[i];
        *(f16x4*)(Xn + cr * 72 + cs * 4) = h;
    }
    BAR();
    l01<2>(w0f, w1f, Xn, 72, H0, H1, mrow, nh, q);
    f32x4 o = l2(w2f, H1, mrow, q);
    f32x4 nv;
#pragma unroll
    for (int i = 0; i < 4; ++i) nv[i] = o[i] + oldv[i];
    *(f32x4*)(node + (t * 32 + mrow) * 32 + col) = nv;
}

// ---------------- decoder: node(32) -> MLP(32->128->128->1) -> fp32 out ----------
__global__ __launch_bounds__(256, 3) void k_dec(
    const float* __restrict__ node,
    const _Float16* __restrict__ w0t, const _Float16* __restrict__ w1t,
    const _Float16* __restrict__ w2t, float* __restrict__ out) {
    __shared__ __align__(16) _Float16 Xd[32 * 40];
    __shared__ __align__(16) _Float16 H0[32 * 136];
    __shared__ __align__(16) _Float16 H1[32 * 136];
    const int tid = threadIdx.x, wave = tid >> 6, lane = tid & 63;
    const int q = lane >> 4, l16 = lane & 15;
    const int mt = wave & 1, nh = wave >> 1;
    const int mrow = mt * 16 + l16;
    f16x8 w0f[1][4], w1f[4][4], w2f[4];
    load_wf4<1>(w0t, 32, nh * 64, l16, q, w0f);
    load_wf4<4>(w1t, 128, nh * 64, l16, q, w1f);
    {
        int n2 = l16;  // padded W2^T is [16][128]; all waves load tile 0
#pragma unroll
        for (int ks = 0; ks < 4; ++ks)
            w2f[ks] = *(const f16x8*)(w2t + n2 * 128 + ks * 32 + q * 8);
    }
    const int t = blockIdx.x;
    const int cr = tid >> 3, cs = tid & 7;
    f32x4 v = *(const f32x4*)(node + (t * 32 + cr) * 32 + cs * 4);
    f16x4 h;
#pragma unroll
    for (int i = 0; i < 4; ++i) h[i] = (_Float16)v[i];
    *(f16x4*)(Xd + cr * 40 + cs * 4) = h;
    BAR();
    l01<1>(w0f, w1f, Xd, 40, H0, H1, mrow, nh, q);
    if (nh == 0) {
        f32x4 o = l2(w2f, H1, mrow, q);
        if (q == 0) out[t * 32 + mrow] = o[0];  // feature n=0: reg 0 of quad 0
    }
}

extern "C" void kernel_launch(void* const* d_in, const int* in_sizes, int n_in,
                              void* d_out, int out_size, void* d_ws, size_t ws_size,
                              hipStream_t stream) {
    const float* input_node = (const float*)d_in[0];
    const float* input_edge = (const float*)d_in[1];
    const int* gi = (const int*)d_in[2];

    _Float16* ws = (_Float16*)d_ws;
    // ws layout (bytes):
    //   weights f16:          [0,          634,880)
    //   node  fp32 32000x32:  [655,360,    4,751,360)
    //   edgeP fp32 512000x32: [4,751,360,  70,287,360)   (receiver-sorted rows)
    //   rowptr u32[32001]:    [70,287,360, 70,415,364)
    //   cursor u32[32000]:    [70,415,616, 70,543,616)
    //   iperm  u32[512000]:   [70,543,616, 72,591,616)
    float* node = (float*)((char*)d_ws + 655360);
    float* edgeP = (float*)((char*)d_ws + 4751360);
    unsigned* rowptr = (unsigned*)((char*)d_ws + 70287360);
    unsigned* cursor = (unsigned*)((char*)d_ws + 70415616);
    unsigned* iperm = (unsigned*)((char*)d_ws + 70543616);

    WPtrs wp;
    for (int i = 0; i < 15; ++i) wp.p[i] = (const float*)d_in[3 + i];

    k_prep<<<33, 256, 0, stream>>>(wp, ws);

    // CSR build (u32 atomics only)
    k_zero<<<125, 256, 0, stream>>>(cursor, 32000);
    k_hist<<<2000, 256, 0, stream>>>(gi, cursor);
    k_scan<<<1, 1024, 0, stream>>>(cursor, rowptr, cursor);
    k_scatter<<<2000, 256, 0, stream>>>(gi, cursor, iperm);

    k_enc<<<1000, 256, 0, stream>>>(input_node, node, ws + 0, ws + 4096, ws + 20480,
                                    1000, nullptr);
    k_enc<<<768, 256, 0, stream>>>(input_edge, edgeP, ws + 24576, ws + 28672,
                                   ws + 45056, 16000, iperm);

    for (int t = 0; t < 4; ++t) {
        k_edge<<<768, 256, 0, stream>>>(node, edgeP, gi, iperm,
                                        ws + 49152 + t * 32768,
                                        ws + 61440 + t * 32768,
                                        ws + 77824 + t * 32768);
        k_node<<<1000, 256, 0, stream>>>(node, edgeP, rowptr,
                                         ws + 180224 + t * 28672,
                                         ws + 188416 + t * 28672,
                                         ws + 204800 + t * 28672);
    }
    k_dec<<<1000, 256, 0, stream>>>(node, ws + 294912, ws + 299008, ws + 315392,
                                    (float*)d_out);
}

// Round 7
// 842.980 us; speedup vs baseline: 1.9275x; 1.2194x over previous
//
#include <hip/hip_runtime.h>

typedef __attribute__((ext_vector_type(8))) _Float16 f16x8;
typedef __attribute__((ext_vector_type(4))) _Float16 f16x4;
typedef __attribute__((ext_vector_type(4))) float f32x4;

#define DI __device__ __forceinline__
// Raw barrier: LDS-drain only (lgkmcnt). Avoids the compiler's vmcnt(0) drain
// that would serialize in-flight register prefetches across the barrier.
#define BAR() asm volatile("s_waitcnt lgkmcnt(0)\n\ts_barrier" ::: "memory")

DI f32x4 mfma16(f16x8 a, f16x8 b, f32x4 c) {
    return __builtin_amdgcn_mfma_f32_16x16x32_f16(a, b, c, 0, 0, 0);
}

// Load weight fragments for 4 n-tiles x NK k-steps. wt is W^T [N][Kp] f16 row-major.
template <int NK>
DI void load_wf4(const _Float16* __restrict__ wt, int Kp, int nbase, int l16, int q,
                 f16x8 f[NK][4]) {
#pragma unroll
    for (int nt = 0; nt < 4; ++nt) {
        int n = nbase + nt * 16 + l16;
#pragma unroll
        for (int ks = 0; ks < NK; ++ks)
            f[ks][nt] = *(const f16x8*)(wt + n * Kp + ks * 32 + q * 8);
    }
}

// Layers 0/1: transposed compute D' = W^T X^T; relu'd f16 to H buffers (stride 136).
template <int NK0>
DI void l01(const f16x8 (*w0f)[4], const f16x8 (*w1f)[4],
            const _Float16* __restrict__ X, int xstride,
            _Float16* __restrict__ H0, _Float16* __restrict__ H1,
            int mrow, int nh, int q) {
    const f32x4 zero = {0.f, 0.f, 0.f, 0.f};
    f32x4 acc[4];
#pragma unroll
    for (int nt = 0; nt < 4; ++nt) acc[nt] = zero;
#pragma unroll
    for (int ks = 0; ks < NK0; ++ks) {
        f16x8 x = *(const f16x8*)(X + mrow * xstride + ks * 32 + q * 8);
#pragma unroll
        for (int nt = 0; nt < 4; ++nt) acc[nt] = mfma16(w0f[ks][nt], x, acc[nt]);
    }
#pragma unroll
    for (int nt = 0; nt < 4; ++nt) {
        f16x4 h;
#pragma unroll
        for (int i = 0; i < 4; ++i) h[i] = (_Float16)fmaxf(acc[nt][i], 0.f);
        *(f16x4*)(H0 + mrow * 136 + nh * 64 + nt * 16 + q * 4) = h;
    }
    BAR();
    f32x4 a1[4];
#pragma unroll
    for (int nt = 0; nt < 4; ++nt) a1[nt] = zero;
#pragma unroll
    for (int ks = 0; ks < 4; ++ks) {
        f16x8 x = *(const f16x8*)(H0 + mrow * 136 + ks * 32 + q * 8);
#pragma unroll
        for (int nt = 0; nt < 4; ++nt) a1[nt] = mfma16(w1f[ks][nt], x, a1[nt]);
    }
#pragma unroll
    for (int nt = 0; nt < 4; ++nt) {
        f16x4 h;
#pragma unroll
        for (int i = 0; i < 4; ++i) h[i] = (_Float16)fmaxf(a1[nt][i], 0.f);
        *(f16x4*)(H1 + mrow * 136 + nh * 64 + nt * 16 + q * 4) = h;
    }
    BAR();
}

DI f32x4 l2(const f16x8* w2f, const _Float16* __restrict__ H1, int mrow, int q) {
    f32x4 acc = {0.f, 0.f, 0.f, 0.f};
#pragma unroll
    for (int ks = 0; ks < 4; ++ks) {
        f16x8 x = *(const f16x8*)(H1 + mrow * 136 + ks * 32 + q * 8);
        acc = mfma16(w2f[ks], x, acc);
    }
    return acc;
}

// ---------------- weight prep: fp32 [K][N] -> f16 W^T [Np][Kp] (zero padded) ----
struct WPtrs { const float* p[15]; };

__global__ void k_prep(WPtrs wp, _Float16* __restrict__ ws) {
    int b = blockIdx.x;
    const float* src; int K, N, Np, Kp, off;
    if (b == 0)       { src = wp.p[0];  K = 3;   N = 128; Np = 128; Kp = 32;  off = 0; }
    else if (b == 1)  { src = wp.p[1];  K = 128; N = 128; Np = 128; Kp = 128; off = 4096; }
    else if (b == 2)  { src = wp.p[2];  K = 128; N = 32;  Np = 32;  Kp = 128; off = 20480; }
    else if (b == 3)  { src = wp.p[3];  K = 3;   N = 128; Np = 128; Kp = 32;  off = 24576; }
    else if (b == 4)  { src = wp.p[4];  K = 128; N = 128; Np = 128; Kp = 128; off = 28672; }
    else if (b == 5)  { src = wp.p[5];  K = 128; N = 32;  Np = 32;  Kp = 128; off = 45056; }
    else if (b <= 9)  { int t = b - 6;  src = wp.p[6] + t * 12288;  K = 96;  N = 128; Np = 128; Kp = 96;  off = 49152 + t * 32768; }
    else if (b <= 13) { int t = b - 10; src = wp.p[7] + t * 16384;  K = 128; N = 128; Np = 128; Kp = 128; off = 61440 + t * 32768; }
    else if (b <= 17) { int t = b - 14; src = wp.p[8] + t * 4096;   K = 128; N = 32;  Np = 32;  Kp = 128; off = 77824 + t * 32768; }
    else if (b <= 21) { int t = b - 18; src = wp.p[9] + t * 8192;   K = 64;  N = 128; Np = 128; Kp = 64;  off = 180224 + t * 28672; }
    else if (b <= 25) { int t = b - 22; src = wp.p[10] + t * 16384; K = 128; N = 128; Np = 128; Kp = 128; off = 188416 + t * 28672; }
    else if (b <= 29) { int t = b - 26; src = wp.p[11] + t * 4096;  K = 128; N = 32;  Np = 32;  Kp = 128; off = 204800 + t * 28672; }
    else if (b == 30) { src = wp.p[12]; K = 32;  N = 128; Np = 128; Kp = 32;  off = 294912; }
    else if (b == 31) { src = wp.p[13]; K = 128; N = 128; Np = 128; Kp = 128; off = 299008; }
    else              { src = wp.p[14]; K = 128; N = 1;   Np = 16;  Kp = 128; off = 315392; }
    int total = Np * Kp;
    for (int i = threadIdx.x; i < total; i += 256) {
        int n = i / Kp, k = i - n * Kp;
        float v = (k < K && n < N) ? src[k * N + n] : 0.f;
        ws[off + i] = (_Float16)v;
    }
}

// ---------------- CSR build: histogram -> scan -> scatter (u32 atomics only) -----
__global__ void k_zero(unsigned* __restrict__ p, int n) {
    int i = blockIdx.x * 256 + threadIdx.x;
    if (i < n) p[i] = 0u;
}
__global__ void k_hist(const int* __restrict__ gi, unsigned* __restrict__ cnt) {
    int e = blockIdx.x * 256 + threadIdx.x;
    if (e < 512000) atomicAdd(&cnt[gi[2 * e + 1]], 1u);
}
// one block, 1024 threads: exclusive scan of cnt[0..32000) -> rowptr, cursor
__global__ __launch_bounds__(1024) void k_scan(
    const unsigned* __restrict__ cnt, unsigned* __restrict__ rowptr,
    unsigned* __restrict__ cursor) {
    __shared__ unsigned s[1024];
    int t = threadIdx.x;
    unsigned loc[32];
    unsigned sum = 0;
#pragma unroll
    for (int i = 0; i < 32; ++i) {
        int idx = t * 32 + i;
        unsigned v = (idx < 32000) ? cnt[idx] : 0u;
        loc[i] = v; sum += v;
    }
    s[t] = sum;
    __syncthreads();
    if (t == 0) {
        unsigned run = 0;
        for (int i = 0; i < 1024; ++i) { unsigned tmp = s[i]; s[i] = run; run += tmp; }
        rowptr[32000] = run;
    }
    __syncthreads();
    unsigned off = s[t];
#pragma unroll
    for (int i = 0; i < 32; ++i) {
        int idx = t * 32 + i;
        if (idx < 32000) { rowptr[idx] = off; cursor[idx] = off; off += loc[i]; }
    }
}
__global__ void k_scatter(const int* __restrict__ gi, unsigned* __restrict__ cursor,
                          unsigned* __restrict__ iperm, int2* __restrict__ sr) {
    int e = blockIdx.x * 256 + threadIdx.x;
    if (e < 512000) {
        int s = gi[2 * e], r = gi[2 * e + 1];
        unsigned pos = atomicAdd(&cursor[r], 1u);
        iperm[pos] = (unsigned)e;
        sr[pos] = make_int2(s, r);
    }
}

// ---------------- encoder: fp32 [M][3] -> MLP -> f16 out rows --------------------
// iperm != nullptr (edge path): row p of out corresponds to original edge iperm[p].
__global__ __launch_bounds__(256, 3) void k_enc(
    const float* __restrict__ in, _Float16* __restrict__ out,
    const _Float16* __restrict__ w0t, const _Float16* __restrict__ w1t,
    const _Float16* __restrict__ w2t, int NT, const unsigned* __restrict__ iperm) {
    __shared__ __align__(16) _Float16 Xp[32 * 40];
    __shared__ __align__(16) _Float16 H0[32 * 136];
    __shared__ __align__(16) _Float16 H1[32 * 136];
    const int tid = threadIdx.x, wave = tid >> 6, lane = tid & 63;
    const int q = lane >> 4, l16 = lane & 15;
    const int mt = wave & 1, nh = wave >> 1;
    const int mrow = mt * 16 + l16;
    const int col = nh * 16 + q * 4;
    f16x8 w0f[1][4], w1f[4][4], w2f[4];
    load_wf4<1>(w0t, 32, nh * 64, l16, q, w0f);
    load_wf4<4>(w1t, 128, nh * 64, l16, q, w1f);
    {
        int n2 = nh * 16 + l16;
#pragma unroll
        for (int ks = 0; ks < 4; ++ks)
            w2f[ks] = *(const f16x8*)(w2t + n2 * 128 + ks * 32 + q * 8);
    }
    for (int c = tid; c < 1280; c += 256) Xp[c] = (_Float16)0.f;
    BAR();

    const int g = gridDim.x;
    const int dr = tid / 3, dc = tid - dr * 3;  // valid when tid<96
    int t = blockIdx.x;
    int tn = t + g; if (tn >= NT) tn = t;
    float v = 0.f;
    if (tid < 96) {
        unsigned e = iperm ? iperm[t * 32 + dr] : (unsigned)(t * 32 + dr);
        v = in[e * 3 + dc];
    }

    while (true) {
        if (tid < 96) Xp[dr * 40 + dc] = (_Float16)v;
        BAR();
        float vn = 0.f;
        if (tid < 96) {
            unsigned e = iperm ? iperm[tn * 32 + dr] : (unsigned)(tn * 32 + dr);
            vn = in[e * 3 + dc];
        }
        l01<1>(w0f, w1f, Xp, 40, H0, H1, mrow, nh, q);
        f32x4 o = l2(w2f, H1, mrow, q);
        f16x4 ov;
#pragma unroll
        for (int i = 0; i < 4; ++i) ov[i] = (_Float16)o[i];
        *(f16x4*)(out + (t * 32 + mrow) * 32 + col) = ov;
        if (tn == t) break;
        t = tn; tn = t + g; if (tn >= NT) tn = t;
        v = vn;
    }
}

// ---------------- edge update: [edge|node_s|node_r](96) -> MLP -> +res -----------
// f16 latents. Rows receiver-sorted. sr[p] = (sender, receiver), read sequentially.
// Staging = pure int4 copies (16 B = 8 f16). 384 chunks/tile: j0 all, j1 tid<128.
__global__ __launch_bounds__(256, 3) void k_edge(
    const _Float16* __restrict__ node, _Float16* __restrict__ edgeP,
    const int2* __restrict__ sr,
    const _Float16* __restrict__ w0t, const _Float16* __restrict__ w1t,
    const _Float16* __restrict__ w2t) {
    __shared__ __align__(16) _Float16 Xe[32 * 104];
    __shared__ __align__(16) _Float16 H0[32 * 136];
    __shared__ __align__(16) _Float16 H1[32 * 136];
    const int tid = threadIdx.x, wave = tid >> 6, lane = tid & 63;
    const int q = lane >> 4, l16 = lane & 15;
    const int mt = wave & 1, nh = wave >> 1;
    const int mrow = mt * 16 + l16;
    const int col = nh * 16 + q * 4;
    f16x8 w0f[3][4], w1f[4][4], w2f[4];
    load_wf4<3>(w0t, 96, nh * 64, l16, q, w0f);
    load_wf4<4>(w1t, 128, nh * 64, l16, q, w1f);
    {
        int n2 = nh * 16 + l16;
#pragma unroll
        for (int ks = 0; ks < 4; ++ks)
            w2f[ks] = *(const f16x8*)(w2t + n2 * 128 + ks * 32 + q * 8);
    }
    int cr[2], cs[2];
    bool cv[2];
#pragma unroll
    for (int j = 0; j < 2; ++j) {
        int c = tid + 256 * j;
        cr[j] = c / 12; cs[j] = c - cr[j] * 12;
        cv[j] = (c < 384);
    }

    const int NT = 16000, g = gridDim.x;
    int t = blockIdx.x;
    int tn = t + g; if (tn >= NT) tn = t;

    int2 srn[2]; int4 v[2]; f16x4 oldv;
    {
        int2 sr0[2];
#pragma unroll
        for (int j = 0; j < 2; ++j)
            if (cv[j]) sr0[j] = sr[t * 32 + cr[j]];
#pragma unroll
        for (int j = 0; j < 2; ++j)
            if (cv[j]) {
                int s = cs[j];
                const _Float16* src = (s < 4) ? edgeP + (t * 32 + cr[j]) * 32 + s * 8
                                   : (s < 8) ? node + sr0[j].x * 32 + (s - 4) * 8
                                             : node + sr0[j].y * 32 + (s - 8) * 8;
                v[j] = *(const int4*)src;
            }
        oldv = *(const f16x4*)(edgeP + (t * 32 + mrow) * 32 + col);
#pragma unroll
        for (int j = 0; j < 2; ++j)
            if (cv[j]) srn[j] = sr[tn * 32 + cr[j]];
    }

    while (true) {
#pragma unroll
        for (int j = 0; j < 2; ++j)
            if (cv[j]) *(int4*)(Xe + cr[j] * 104 + cs[j] * 8) = v[j];
        BAR();
        int tn2 = tn + g; if (tn2 >= NT) tn2 = tn;
        int4 vn[2]; f16x4 oldn; int2 sr2[2];
#pragma unroll
        for (int j = 0; j < 2; ++j)
            if (cv[j]) {
                int s = cs[j];
                const _Float16* src = (s < 4) ? edgeP + (tn * 32 + cr[j]) * 32 + s * 8
                                   : (s < 8) ? node + srn[j].x * 32 + (s - 4) * 8
                                             : node + srn[j].y * 32 + (s - 8) * 8;
                vn[j] = *(const int4*)src;
            }
        oldn = *(const f16x4*)(edgeP + (tn * 32 + mrow) * 32 + col);
#pragma unroll
        for (int j = 0; j < 2; ++j)
            if (cv[j]) sr2[j] = sr[tn2 * 32 + cr[j]];

        l01<3>(w0f, w1f, Xe, 104, H0, H1, mrow, nh, q);
        f32x4 o = l2(w2f, H1, mrow, q);
        f16x4 nv;
#pragma unroll
        for (int i = 0; i < 4; ++i) nv[i] = (_Float16)(o[i] + (float)oldv[i]);
        *(f16x4*)(edgeP + (t * 32 + mrow) * 32 + col) = nv;

        if (tn == t) break;
        t = tn; tn = tn2;
#pragma unroll
        for (int j = 0; j < 2; ++j) { v[j] = vn[j]; srn[j] = sr2[j]; }
        oldv = oldn;
    }
}

// ---------------- node update: [node|csr_sum(edgeP)](64) -> MLP -> +res ----------
// One tile per block. Aggregation = contiguous fp32 segment sum over f16 rows.
__global__ __launch_bounds__(256, 3) void k_node(
    _Float16* __restrict__ node, const _Float16* __restrict__ edgeP,
    const unsigned* __restrict__ rowptr,
    const _Float16* __restrict__ w0t, const _Float16* __restrict__ w1t,
    const _Float16* __restrict__ w2t) {
    __shared__ __align__(16) _Float16 Xn[32 * 72];
    __shared__ __align__(16) _Float16 H0[32 * 136];
    __shared__ __align__(16) _Float16 H1[32 * 136];
    const int tid = threadIdx.x, wave = tid >> 6, lane = tid & 63;
    const int q = lane >> 4, l16 = lane & 15;
    const int mt = wave & 1, nh = wave >> 1;
    const int mrow = mt * 16 + l16;
    const int col = nh * 16 + q * 4;
    f16x8 w0f[2][4], w1f[4][4], w2f[4];
    load_wf4<2>(w0t, 64, nh * 64, l16, q, w0f);
    load_wf4<4>(w1t, 128, nh * 64, l16, q, w1f);
    {
        int n2 = nh * 16 + l16;
#pragma unroll
        for (int ks = 0; ks < 4; ++ks)
            w2f[ks] = *(const f16x8*)(w2t + n2 * 128 + ks * 32 + q * 8);
    }
    const int t = blockIdx.x;
    f16x4 oldv = *(const f16x4*)(node + (t * 32 + mrow) * 32 + col);
    // 8 chunks/row (16 B each): cs<4 node copy, cs>=4 segment-sum of edgeP chunk
    {
        int cr = tid >> 3, cs = tid & 7;
        int r = t * 32 + cr;
        if (cs < 4) {
            *(int4*)(Xn + cr * 72 + cs * 8) = *(const int4*)(node + r * 32 + cs * 8);
        } else {
            unsigned b = rowptr[r], e = rowptr[r + 1];
            const _Float16* base = edgeP + (cs - 4) * 8;
            float a0[8], a1[8];
#pragma unroll
            for (int i = 0; i < 8; ++i) { a0[i] = 0.f; a1[i] = 0.f; }
            unsigned p = b;
            for (; p + 2 <= e; p += 2) {
                f16x8 x0 = *(const f16x8*)(base + (p + 0) * 32);
                f16x8 x1 = *(const f16x8*)(base + (p + 1) * 32);
#pragma unroll
                for (int i = 0; i < 8; ++i) { a0[i] += (float)x0[i]; a1[i] += (float)x1[i]; }
            }
            if (p < e) {
                f16x8 x0 = *(const f16x8*)(base + p * 32);
#pragma unroll
                for (int i = 0; i < 8; ++i) a0[i] += (float)x0[i];
            }
            f16x8 h;
#pragma unroll
            for (int i = 0; i < 8; ++i) h[i] = (_Float16)(a0[i] + a1[i]);
            *(f16x8*)(Xn + cr * 72 + cs * 8) = h;
        }
    }
    BAR();
    l01<2>(w0f, w1f, Xn, 72, H0, H1, mrow, nh, q);
    f32x4 o = l2(w2f, H1, mrow, q);
    f16x4 nv;
#pragma unroll
    for (int i = 0; i < 4; ++i) nv[i] = (_Float16)(o[i] + (float)oldv[i]);
    *(f16x4*)(node + (t * 32 + mrow) * 32 + col) = nv;
}

// ---------------- decoder: node(32) -> MLP(32->128->128->1) -> fp32 out ----------
__global__ __launch_bounds__(256, 3) void k_dec(
    const _Float16* __restrict__ node,
    const _Float16* __restrict__ w0t, const _Float16* __restrict__ w1t,
    const _Float16* __restrict__ w2t, float* __restrict__ out) {
    __shared__ __align__(16) _Float16 Xd[32 * 40];
    __shared__ __align__(16) _Float16 H0[32 * 136];
    __shared__ __align__(16) _Float16 H1[32 * 136];
    const int tid = threadIdx.x, wave = tid >> 6, lane = tid & 63;
    const int q = lane >> 4, l16 = lane & 15;
    const int mt = wave & 1, nh = wave >> 1;
    const int mrow = mt * 16 + l16;
    f16x8 w0f[1][4], w1f[4][4], w2f[4];
    load_wf4<1>(w0t, 32, nh * 64, l16, q, w0f);
    load_wf4<4>(w1t, 128, nh * 64, l16, q, w1f);
    {
        int n2 = l16;  // padded W2^T is [16][128]; all waves load tile 0
#pragma unroll
        for (int ks = 0; ks < 4; ++ks)
            w2f[ks] = *(const f16x8*)(w2t + n2 * 128 + ks * 32 + q * 8);
    }
    const int t = blockIdx.x;
    if (tid < 128) {
        int cr = tid >> 2, cs = tid & 3;
        *(int4*)(Xd + cr * 40 + cs * 8) = *(const int4*)(node + (t * 32 + cr) * 32 + cs * 8);
    }
    BAR();
    l01<1>(w0f, w1f, Xd, 40, H0, H1, mrow, nh, q);
    if (nh == 0) {
        f32x4 o = l2(w2f, H1, mrow, q);
        if (q == 0) out[t * 32 + mrow] = o[0];  // feature n=0: reg 0 of quad 0
    }
}

extern "C" void kernel_launch(void* const* d_in, const int* in_sizes, int n_in,
                              void* d_out, int out_size, void* d_ws, size_t ws_size,
                              hipStream_t stream) {
    const float* input_node = (const float*)d_in[0];
    const float* input_edge = (const float*)d_in[1];
    const int* gi = (const int*)d_in[2];

    _Float16* ws = (_Float16*)d_ws;
    // ws layout (bytes):
    //   weights f16:         [0,          634,880)
    //   node  f16 32000x32:  [655,360,    2,703,360)
    //   edgeP f16 512000x32: [2,703,360,  35,471,360)   (receiver-sorted rows)
    //   rowptr u32[32001]:   [35,471,360, 35,599,364)
    //   cursor u32[32000]:   [35,599,616, 35,727,616)
    //   iperm  u32[512000]:  [35,727,616, 37,775,616)
    //   sr   int2[512000]:   [37,775,616, 41,871,616)
    _Float16* node = (_Float16*)((char*)d_ws + 655360);
    _Float16* edgeP = (_Float16*)((char*)d_ws + 2703360);
    unsigned* rowptr = (unsigned*)((char*)d_ws + 35471360);
    unsigned* cursor = (unsigned*)((char*)d_ws + 35599616);
    unsigned* iperm = (unsigned*)((char*)d_ws + 35727616);
    int2* sr = (int2*)((char*)d_ws + 37775616);

    WPtrs wp;
    for (int i = 0; i < 15; ++i) wp.p[i] = (const float*)d_in[3 + i];

    k_prep<<<33, 256, 0, stream>>>(wp, ws);

    // CSR build (u32 atomics only)
    k_zero<<<125, 256, 0, stream>>>(cursor, 32000);
    k_hist<<<2000, 256, 0, stream>>>(gi, cursor);
    k_scan<<<1, 1024, 0, stream>>>(cursor, rowptr, cursor);
    k_scatter<<<2000, 256, 0, stream>>>(gi, cursor, iperm, sr);

    k_enc<<<1000, 256, 0, stream>>>(input_node, node, ws + 0, ws + 4096, ws + 20480,
                                    1000, nullptr);
    k_enc<<<768, 256, 0, stream>>>(input_edge, edgeP, ws + 24576, ws + 28672,
                                   ws + 45056, 16000, iperm);

    for (int t = 0; t < 4; ++t) {
        k_edge<<<768, 256, 0, stream>>>(node, edgeP, sr,
                                        ws + 49152 + t * 32768,
                                        ws + 61440 + t * 32768,
                                        ws + 77824 + t * 32768);
        k_node<<<1000, 256, 0, stream>>>(node, edgeP, rowptr,
                                         ws + 180224 + t * 28672,
                                         ws + 188416 + t * 28672,
                                         ws + 204800 + t * 28672);
    }
    k_dec<<<1000, 256, 0, stream>>>(node, ws + 294912, ws + 299008, ws + 315392,
                                    (float*)d_out);
}

// Round 8
// 704.971 us; speedup vs baseline: 2.3049x; 1.1958x over previous
//
#include <hip/hip_runtime.h>

typedef __attribute__((ext_vector_type(8))) _Float16 f16x8;
typedef __attribute__((ext_vector_type(4))) _Float16 f16x4;
typedef __attribute__((ext_vector_type(4))) float f32x4;

#define DI __device__ __forceinline__
// Raw barrier: LDS-drain only (lgkmcnt). Avoids the compiler's vmcnt(0) drain
// that would serialize in-flight register prefetches across the barrier.
#define BAR() asm volatile("s_waitcnt lgkmcnt(0)\n\ts_barrier" ::: "memory")

DI f32x4 mfma16(f16x8 a, f16x8 b, f32x4 c) {
    return __builtin_amdgcn_mfma_f32_16x16x32_f16(a, b, c, 0, 0, 0);
}

// Wave-mapping (R8): wave w owns features [w*32, w*32+32) for layers 0/1 (2 n-tiles,
// weight frags reused across both m-halves). Layer 2: wave w computes rows
// (w>>1)*16.. and cols (w&1)*16.. of the 32x32 output.
// Per-wave weight regs: l0 NK0*2 + l1 4*2 + l2 4 frags -> 72 VGPRs for k_edge.

// Load weight fragments for 2 n-tiles x NK k-steps. wt is W^T [N][Kp] f16 row-major.
template <int NK>
DI void load_wf2(const _Float16* __restrict__ wt, int Kp, int nbase, int l16, int q,
                 f16x8 f[NK][2]) {
#pragma unroll
    for (int nt = 0; nt < 2; ++nt) {
        int n = nbase + nt * 16 + l16;
#pragma unroll
        for (int ks = 0; ks < NK; ++ks)
            f[ks][nt] = *(const f16x8*)(wt + n * Kp + ks * 32 + q * 8);
    }
}

// Layers 0/1: transposed compute D' = W^T X^T; relu'd f16 to H buffers (stride 136).
template <int NK0>
DI void l01(const f16x8 (*w0f)[2], const f16x8 (*w1f)[2],
            const _Float16* __restrict__ X, int xstride,
            _Float16* __restrict__ H0, _Float16* __restrict__ H1,
            int l16, int w, int q) {
    const f32x4 zero = {0.f, 0.f, 0.f, 0.f};
    f32x4 acc[2][2];
#pragma unroll
    for (int nt = 0; nt < 2; ++nt) { acc[nt][0] = zero; acc[nt][1] = zero; }
#pragma unroll
    for (int ks = 0; ks < NK0; ++ks) {
        f16x8 x0 = *(const f16x8*)(X + l16 * xstride + ks * 32 + q * 8);
        f16x8 x1 = *(const f16x8*)(X + (16 + l16) * xstride + ks * 32 + q * 8);
#pragma unroll
        for (int nt = 0; nt < 2; ++nt) {
            acc[nt][0] = mfma16(w0f[ks][nt], x0, acc[nt][0]);
            acc[nt][1] = mfma16(w0f[ks][nt], x1, acc[nt][1]);
        }
    }
#pragma unroll
    for (int mt = 0; mt < 2; ++mt)
#pragma unroll
        for (int nt = 0; nt < 2; ++nt) {
            f16x4 h;
#pragma unroll
            for (int i = 0; i < 4; ++i) h[i] = (_Float16)fmaxf(acc[nt][mt][i], 0.f);
            *(f16x4*)(H0 + (mt * 16 + l16) * 136 + w * 32 + nt * 16 + q * 4) = h;
        }
    BAR();
    f32x4 a1[2][2];
#pragma unroll
    for (int nt = 0; nt < 2; ++nt) { a1[nt][0] = zero; a1[nt][1] = zero; }
#pragma unroll
    for (int ks = 0; ks < 4; ++ks) {
        f16x8 x0 = *(const f16x8*)(H0 + l16 * 136 + ks * 32 + q * 8);
        f16x8 x1 = *(const f16x8*)(H0 + (16 + l16) * 136 + ks * 32 + q * 8);
#pragma unroll
        for (int nt = 0; nt < 2; ++nt) {
            a1[nt][0] = mfma16(w1f[ks][nt], x0, a1[nt][0]);
            a1[nt][1] = mfma16(w1f[ks][nt], x1, a1[nt][1]);
        }
    }
#pragma unroll
    for (int mt = 0; mt < 2; ++mt)
#pragma unroll
        for (int nt = 0; nt < 2; ++nt) {
            f16x4 h;
#pragma unroll
            for (int i = 0; i < 4; ++i) h[i] = (_Float16)fmaxf(a1[nt][mt][i], 0.f);
            *(f16x4*)(H1 + (mt * 16 + l16) * 136 + w * 32 + nt * 16 + q * 4) = h;
        }
    BAR();
}

// Layer 2: wave w -> rows (w>>1)*16+l16, cols (w&1)*16 + q*4 + i.
DI f32x4 l2(const f16x8* w2f, const _Float16* __restrict__ H1, int l16, int w, int q) {
    int m = (w >> 1) * 16 + l16;
    f32x4 acc = {0.f, 0.f, 0.f, 0.f};
#pragma unroll
    for (int ks = 0; ks < 4; ++ks) {
        f16x8 x = *(const f16x8*)(H1 + m * 136 + ks * 32 + q * 8);
        acc = mfma16(w2f[ks], x, acc);
    }
    return acc;
}

// ---------------- weight prep: fp32 [K][N] -> f16 W^T [Np][Kp] (zero padded) ----
struct WPtrs { const float* p[15]; };

__global__ void k_prep(WPtrs wp, _Float16* __restrict__ ws) {
    int b = blockIdx.x;
    const float* src; int K, N, Np, Kp, off;
    if (b == 0)       { src = wp.p[0];  K = 3;   N = 128; Np = 128; Kp = 32;  off = 0; }
    else if (b == 1)  { src = wp.p[1];  K = 128; N = 128; Np = 128; Kp = 128; off = 4096; }
    else if (b == 2)  { src = wp.p[2];  K = 128; N = 32;  Np = 32;  Kp = 128; off = 20480; }
    else if (b == 3)  { src = wp.p[3];  K = 3;   N = 128; Np = 128; Kp = 32;  off = 24576; }
    else if (b == 4)  { src = wp.p[4];  K = 128; N = 128; Np = 128; Kp = 128; off = 28672; }
    else if (b == 5)  { src = wp.p[5];  K = 128; N = 32;  Np = 32;  Kp = 128; off = 45056; }
    else if (b <= 9)  { int t = b - 6;  src = wp.p[6] + t * 12288;  K = 96;  N = 128; Np = 128; Kp = 96;  off = 49152 + t * 32768; }
    else if (b <= 13) { int t = b - 10; src = wp.p[7] + t * 16384;  K = 128; N = 128; Np = 128; Kp = 128; off = 61440 + t * 32768; }
    else if (b <= 17) { int t = b - 14; src = wp.p[8] + t * 4096;   K = 128; N = 32;  Np = 32;  Kp = 128; off = 77824 + t * 32768; }
    else if (b <= 21) { int t = b - 18; src = wp.p[9] + t * 8192;   K = 64;  N = 128; Np = 128; Kp = 64;  off = 180224 + t * 28672; }
    else if (b <= 25) { int t = b - 22; src = wp.p[10] + t * 16384; K = 128; N = 128; Np = 128; Kp = 128; off = 188416 + t * 28672; }
    else if (b <= 29) { int t = b - 26; src = wp.p[11] + t * 4096;  K = 128; N = 32;  Np = 32;  Kp = 128; off = 204800 + t * 28672; }
    else if (b == 30) { src = wp.p[12]; K = 32;  N = 128; Np = 128; Kp = 32;  off = 294912; }
    else if (b == 31) { src = wp.p[13]; K = 128; N = 128; Np = 128; Kp = 128; off = 299008; }
    else              { src = wp.p[14]; K = 128; N = 1;   Np = 16;  Kp = 128; off = 315392; }
    int total = Np * Kp;
    for (int i = threadIdx.x; i < total; i += 256) {
        int n = i / Kp, k = i - n * Kp;
        float v = (k < K && n < N) ? src[k * N + n] : 0.f;
        ws[off + i] = (_Float16)v;
    }
}

// ---------------- CSR build: histogram -> scan -> scatter (u32 atomics only) -----
__global__ void k_zero(unsigned* __restrict__ p, int n) {
    int i = blockIdx.x * 256 + threadIdx.x;
    if (i < n) p[i] = 0u;
}
__global__ void k_hist(const int* __restrict__ gi, unsigned* __restrict__ cnt) {
    int e = blockIdx.x * 256 + threadIdx.x;
    if (e < 512000) atomicAdd(&cnt[gi[2 * e + 1]], 1u);
}
// one block, 1024 threads: exclusive scan of cnt[0..32000) -> rowptr, cursor
__global__ __launch_bounds__(1024) void k_scan(
    const unsigned* __restrict__ cnt, unsigned* __restrict__ rowptr,
    unsigned* __restrict__ cursor) {
    __shared__ unsigned s[1024];
    int t = threadIdx.x;
    unsigned loc[32];
    unsigned sum = 0;
#pragma unroll
    for (int i = 0; i < 32; ++i) {
        int idx = t * 32 + i;
        unsigned v = (idx < 32000) ? cnt[idx] : 0u;
        loc[i] = v; sum += v;
    }
    s[t] = sum;
    __syncthreads();
    if (t == 0) {
        unsigned run = 0;
        for (int i = 0; i < 1024; ++i) { unsigned tmp = s[i]; s[i] = run; run += tmp; }
        rowptr[32000] = run;
    }
    __syncthreads();
    unsigned off = s[t];
#pragma unroll
    for (int i = 0; i < 32; ++i) {
        int idx = t * 32 + i;
        if (idx < 32000) { rowptr[idx] = off; cursor[idx] = off; off += loc[i]; }
    }
}
__global__ void k_scatter(const int* __restrict__ gi, unsigned* __restrict__ cursor,
                          unsigned* __restrict__ iperm, int2* __restrict__ sr) {
    int e = blockIdx.x * 256 + threadIdx.x;
    if (e < 512000) {
        int s = gi[2 * e], r = gi[2 * e + 1];
        unsigned pos = atomicAdd(&cursor[r], 1u);
        iperm[pos] = (unsigned)e;
        sr[pos] = make_int2(s, r);
    }
}

// ---------------- encoder: fp32 [M][3] -> MLP -> f16 out rows --------------------
// iperm != nullptr (edge path): row p of out corresponds to original edge iperm[p].
__global__ __launch_bounds__(256, 3) void k_enc(
    const float* __restrict__ in, _Float16* __restrict__ out,
    const _Float16* __restrict__ w0t, const _Float16* __restrict__ w1t,
    const _Float16* __restrict__ w2t, int NT, const unsigned* __restrict__ iperm) {
    __shared__ __align__(16) _Float16 Xp[32 * 40];
    __shared__ __align__(16) _Float16 H0[32 * 136];
    __shared__ __align__(16) _Float16 H1[32 * 136];
    const int tid = threadIdx.x, w = tid >> 6, lane = tid & 63;
    const int q = lane >> 4, l16 = lane & 15;
    f16x8 w0f[1][2], w1f[4][2], w2f[4];
    load_wf2<1>(w0t, 32, w * 32, l16, q, w0f);
    load_wf2<4>(w1t, 128, w * 32, l16, q, w1f);
    {
        int n2 = (w & 1) * 16 + l16;
#pragma unroll
        for (int ks = 0; ks < 4; ++ks)
            w2f[ks] = *(const f16x8*)(w2t + n2 * 128 + ks * 32 + q * 8);
    }
    for (int c = tid; c < 1280; c += 256) Xp[c] = (_Float16)0.f;
    BAR();

    const int g = gridDim.x;
    const int dr = tid / 3, dc = tid - dr * 3;  // valid when tid<96
    const int orow = (w >> 1) * 16 + l16, ocol = (w & 1) * 16 + q * 4;
    int t = blockIdx.x;
    int tn = t + g; if (tn >= NT) tn = t;
    float v = 0.f;
    if (tid < 96) {
        unsigned e = iperm ? iperm[t * 32 + dr] : (unsigned)(t * 32 + dr);
        v = in[e * 3 + dc];
    }

    while (true) {
        if (tid < 96) Xp[dr * 40 + dc] = (_Float16)v;
        BAR();
        float vn = 0.f;
        if (tid < 96) {
            unsigned e = iperm ? iperm[tn * 32 + dr] : (unsigned)(tn * 32 + dr);
            vn = in[e * 3 + dc];
        }
        l01<1>(w0f, w1f, Xp, 40, H0, H1, l16, w, q);
        f32x4 o = l2(w2f, H1, l16, w, q);
        f16x4 ov;
#pragma unroll
        for (int i = 0; i < 4; ++i) ov[i] = (_Float16)o[i];
        *(f16x4*)(out + (t * 32 + orow) * 32 + ocol) = ov;
        if (tn == t) break;
        t = tn; tn = t + g; if (tn >= NT) tn = t;
        v = vn;
    }
}

// ---------------- edge update: [edge|node_s|node_r](96) -> MLP -> +res -----------
// f16 latents. Rows receiver-sorted. sr[p] = (sender, receiver), read sequentially.
__global__ __launch_bounds__(256, 3) void k_edge(
    const _Float16* __restrict__ node, _Float16* __restrict__ edgeP,
    const int2* __restrict__ sr,
    const _Float16* __restrict__ w0t, const _Float16* __restrict__ w1t,
    const _Float16* __restrict__ w2t) {
    __shared__ __align__(16) _Float16 Xe[32 * 104];
    __shared__ __align__(16) _Float16 H0[32 * 136];
    __shared__ __align__(16) _Float16 H1[32 * 136];
    const int tid = threadIdx.x, w = tid >> 6, lane = tid & 63;
    const int q = lane >> 4, l16 = lane & 15;
    f16x8 w0f[3][2], w1f[4][2], w2f[4];
    load_wf2<3>(w0t, 96, w * 32, l16, q, w0f);
    load_wf2<4>(w1t, 128, w * 32, l16, q, w1f);
    {
        int n2 = (w & 1) * 16 + l16;
#pragma unroll
        for (int ks = 0; ks < 4; ++ks)
            w2f[ks] = *(const f16x8*)(w2t + n2 * 128 + ks * 32 + q * 8);
    }
    int cr[2], cs[2];
    bool cv[2];
#pragma unroll
    for (int j = 0; j < 2; ++j) {
        int c = tid + 256 * j;
        cr[j] = c / 12; cs[j] = c - cr[j] * 12;
        cv[j] = (c < 384);
    }
    const int orow = (w >> 1) * 16 + l16, ocol = (w & 1) * 16 + q * 4;

    const int NT = 16000, g = gridDim.x;
    int t = blockIdx.x;
    int tn = t + g; if (tn >= NT) tn = t;

    int2 srn[2]; int4 v[2]; f16x4 oldv;
    {
        int2 sr0[2];
#pragma unroll
        for (int j = 0; j < 2; ++j)
            if (cv[j]) sr0[j] = sr[t * 32 + cr[j]];
#pragma unroll
        for (int j = 0; j < 2; ++j)
            if (cv[j]) {
                int s = cs[j];
                const _Float16* src = (s < 4) ? edgeP + (t * 32 + cr[j]) * 32 + s * 8
                                   : (s < 8) ? node + sr0[j].x * 32 + (s - 4) * 8
                                             : node + sr0[j].y * 32 + (s - 8) * 8;
                v[j] = *(const int4*)src;
            }
        oldv = *(const f16x4*)(edgeP + (t * 32 + orow) * 32 + ocol);
#pragma unroll
        for (int j = 0; j < 2; ++j)
            if (cv[j]) srn[j] = sr[tn * 32 + cr[j]];
    }

    while (true) {
#pragma unroll
        for (int j = 0; j < 2; ++j)
            if (cv[j]) *(int4*)(Xe + cr[j] * 104 + cs[j] * 8) = v[j];
        BAR();
        int tn2 = tn + g; if (tn2 >= NT) tn2 = tn;
        int4 vn[2]; f16x4 oldn; int2 sr2[2];
#pragma unroll
        for (int j = 0; j < 2; ++j)
            if (cv[j]) {
                int s = cs[j];
                const _Float16* src = (s < 4) ? edgeP + (tn * 32 + cr[j]) * 32 + s * 8
                                   : (s < 8) ? node + srn[j].x * 32 + (s - 4) * 8
                                             : node + srn[j].y * 32 + (s - 8) * 8;
                vn[j] = *(const int4*)src;
            }
        oldn = *(const f16x4*)(edgeP + (tn * 32 + orow) * 32 + ocol);
#pragma unroll
        for (int j = 0; j < 2; ++j)
            if (cv[j]) sr2[j] = sr[tn2 * 32 + cr[j]];

        l01<3>(w0f, w1f, Xe, 104, H0, H1, l16, w, q);
        f32x4 o = l2(w2f, H1, l16, w, q);
        f16x4 nv;
#pragma unroll
        for (int i = 0; i < 4; ++i) nv[i] = (_Float16)(o[i] + (float)oldv[i]);
        *(f16x4*)(edgeP + (t * 32 + orow) * 32 + ocol) = nv;

        if (tn == t) break;
        t = tn; tn = tn2;
#pragma unroll
        for (int j = 0; j < 2; ++j) { v[j] = vn[j]; srn[j] = sr2[j]; }
        oldv = oldn;
    }
}

// ---------------- node update: [node|csr_sum(edgeP)](64) -> MLP -> +res ----------
// One tile per block. Aggregation = contiguous fp32 segment sum over f16 rows.
__global__ __launch_bounds__(256, 3) void k_node(
    _Float16* __restrict__ node, const _Float16* __restrict__ edgeP,
    const unsigned* __restrict__ rowptr,
    const _Float16* __restrict__ w0t, const _Float16* __restrict__ w1t,
    const _Float16* __restrict__ w2t) {
    __shared__ __align__(16) _Float16 Xn[32 * 72];
    __shared__ __align__(16) _Float16 H0[32 * 136];
    __shared__ __align__(16) _Float16 H1[32 * 136];
    const int tid = threadIdx.x, w = tid >> 6, lane = tid & 63;
    const int q = lane >> 4, l16 = lane & 15;
    f16x8 w0f[2][2], w1f[4][2], w2f[4];
    load_wf2<2>(w0t, 64, w * 32, l16, q, w0f);
    load_wf2<4>(w1t, 128, w * 32, l16, q, w1f);
    {
        int n2 = (w & 1) * 16 + l16;
#pragma unroll
        for (int ks = 0; ks < 4; ++ks)
            w2f[ks] = *(const f16x8*)(w2t + n2 * 128 + ks * 32 + q * 8);
    }
    const int t = blockIdx.x;
    const int orow = (w >> 1) * 16 + l16, ocol = (w & 1) * 16 + q * 4;
    f16x4 oldv = *(const f16x4*)(node + (t * 32 + orow) * 32 + ocol);
    // 8 chunks/row (16 B each): cs<4 node copy, cs>=4 segment-sum of edgeP chunk
    {
        int cr = tid >> 3, cs = tid & 7;
        int r = t * 32 + cr;
        if (cs < 4) {
            *(int4*)(Xn + cr * 72 + cs * 8) = *(const int4*)(node + r * 32 + cs * 8);
        } else {
            unsigned b = rowptr[r], e = rowptr[r + 1];
            const _Float16* base = edgeP + (cs - 4) * 8;
            float a0[8], a1[8];
#pragma unroll
            for (int i = 0; i < 8; ++i) { a0[i] = 0.f; a1[i] = 0.f; }
            unsigned p = b;
            for (; p + 2 <= e; p += 2) {
                f16x8 x0 = *(const f16x8*)(base + (p + 0) * 32);
                f16x8 x1 = *(const f16x8*)(base + (p + 1) * 32);
#pragma unroll
                for (int i = 0; i < 8; ++i) { a0[i] += (float)x0[i]; a1[i] += (float)x1[i]; }
            }
            if (p < e) {
                f16x8 x0 = *(const f16x8*)(base + p * 32);
#pragma unroll
                for (int i = 0; i < 8; ++i) a0[i] += (float)x0[i];
            }
            f16x8 h;
#pragma unroll
            for (int i = 0; i < 8; ++i) h[i] = (_Float16)(a0[i] + a1[i]);
            *(f16x8*)(Xn + cr * 72 + cs * 8) = h;
        }
    }
    BAR();
    l01<2>(w0f, w1f, Xn, 72, H0, H1, l16, w, q);
    f32x4 o = l2(w2f, H1, l16, w, q);
    f16x4 nv;
#pragma unroll
    for (int i = 0; i < 4; ++i) nv[i] = (_Float16)(o[i] + (float)oldv[i]);
    *(f16x4*)(node + (t * 32 + orow) * 32 + ocol) = nv;
}

// ---------------- decoder: node(32) -> MLP(32->128->128->1) -> fp32 out ----------
__global__ __launch_bounds__(256, 3) void k_dec(
    const _Float16* __restrict__ node,
    const _Float16* __restrict__ w0t, const _Float16* __restrict__ w1t,
    const _Float16* __restrict__ w2t, float* __restrict__ out) {
    __shared__ __align__(16) _Float16 Xd[32 * 40];
    __shared__ __align__(16) _Float16 H0[32 * 136];
    __shared__ __align__(16) _Float16 H1[32 * 136];
    const int tid = threadIdx.x, w = tid >> 6, lane = tid & 63;
    const int q = lane >> 4, l16 = lane & 15;
    f16x8 w0f[1][2], w1f[4][2], w2f[4];
    load_wf2<1>(w0t, 32, w * 32, l16, q, w0f);
    load_wf2<4>(w1t, 128, w * 32, l16, q, w1f);
    {
        int n2 = l16;  // padded W2^T is [16][128]; all waves load tile 0
#pragma unroll
        for (int ks = 0; ks < 4; ++ks)
            w2f[ks] = *(const f16x8*)(w2t + n2 * 128 + ks * 32 + q * 8);
    }
    const int t = blockIdx.x;
    if (tid < 128) {
        int cr = tid >> 2, cs = tid & 3;
        *(int4*)(Xd + cr * 40 + cs * 8) = *(const int4*)(node + (t * 32 + cr) * 32 + cs * 8);
    }
    BAR();
    l01<1>(w0f, w1f, Xd, 40, H0, H1, l16, w, q);
    f32x4 o = l2(w2f, H1, l16, w, q);
    // only col 0 is real: waves with (w&1)==0, lanes q==0, reg 0
    if ((w & 1) == 0 && q == 0) out[t * 32 + (w >> 1) * 16 + l16] = o[0];
}

extern "C" void kernel_launch(void* const* d_in, const int* in_sizes, int n_in,
                              void* d_out, int out_size, void* d_ws, size_t ws_size,
                              hipStream_t stream) {
    const float* input_node = (const float*)d_in[0];
    const float* input_edge = (const float*)d_in[1];
    const int* gi = (const int*)d_in[2];

    _Float16* ws = (_Float16*)d_ws;
    // ws layout (bytes):
    //   weights f16:         [0,          634,880)
    //   node  f16 32000x32:  [655,360,    2,703,360)
    //   edgeP f16 512000x32: [2,703,360,  35,471,360)   (receiver-sorted rows)
    //   rowptr u32[32001]:   [35,471,360, 35,599,364)
    //   cursor u32[32000]:   [35,599,616, 35,727,616)
    //   iperm  u32[512000]:  [35,727,616, 37,775,616)
    //   sr   int2[512000]:   [37,775,616, 41,871,616)
    _Float16* node = (_Float16*)((char*)d_ws + 655360);
    _Float16* edgeP = (_Float16*)((char*)d_ws + 2703360);
    unsigned* rowptr = (unsigned*)((char*)d_ws + 35471360);
    unsigned* cursor = (unsigned*)((char*)d_ws + 35599616);
    unsigned* iperm = (unsigned*)((char*)d_ws + 35727616);
    int2* sr = (int2*)((char*)d_ws + 37775616);

    WPtrs wp;
    for (int i = 0; i < 15; ++i) wp.p[i] = (const float*)d_in[3 + i];

    k_prep<<<33, 256, 0, stream>>>(wp, ws);

    // CSR build (u32 atomics only)
    k_zero<<<125, 256, 0, stream>>>(cursor, 32000);
    k_hist<<<2000, 256, 0, stream>>>(gi, cursor);
    k_scan<<<1, 1024, 0, stream>>>(cursor, rowptr, cursor);
    k_scatter<<<2000, 256, 0, stream>>>(gi, cursor, iperm, sr);

    k_enc<<<1000, 256, 0, stream>>>(input_node, node, ws + 0, ws + 4096, ws + 20480,
                                    1000, nullptr);
    k_enc<<<768, 256, 0, stream>>>(input_edge, edgeP, ws + 24576, ws + 28672,
                                   ws + 45056, 16000, iperm);

    for (int t = 0; t < 4; ++t) {
        k_edge<<<768, 256, 0, stream>>>(node, edgeP, sr,
                                        ws + 49152 + t * 32768,
                                        ws + 61440 + t * 32768,
                                        ws + 77824 + t * 32768);
        k_node<<<1000, 256, 0, stream>>>(node, edgeP, rowptr,
                                         ws + 180224 + t * 28672,
                                         ws + 188416 + t * 28672,
                                         ws + 204800 + t * 28672);
    }
    k_dec<<<1000, 256, 0, stream>>>(node, ws + 294912, ws + 299008, ws + 315392,
                                    (float*)d_out);
}

// Round 9
// 643.306 us; speedup vs baseline: 2.5258x; 1.0959x over previous
//
#include <hip/hip_runtime.h>

typedef __attribute__((ext_vector_type(8))) _Float16 f16x8;
typedef __attribute__((ext_vector_type(4))) _Float16 f16x4;
typedef __attribute__((ext_vector_type(4))) float f32x4;

#define DI __device__ __forceinline__
// Raw barrier: LDS-drain only (lgkmcnt). Avoids the compiler's vmcnt(0) drain
// that would serialize in-flight register prefetches across the barrier.
#define BAR() asm volatile("s_waitcnt lgkmcnt(0)\n\ts_barrier" ::: "memory")

DI f32x4 mfma16(f16x8 a, f16x8 b, f32x4 c) {
    return __builtin_amdgcn_mfma_f32_16x16x32_f16(a, b, c, 0, 0, 0);
}

// Wave-mapping: wave w owns features [w*32, w*32+32) for layers 0/1 (2 n-tiles,
// weight frags reused across all MH m-groups of 16 rows). Layer 2: wave w computes
// rows (w>>1)*16 (+32*g) and cols (w&1)*16 of the MHx16 x 32 output.

// Load weight fragments for 2 n-tiles x NK k-steps. wt is W^T [N][Kp] f16 row-major.
template <int NK>
DI void load_wf2(const _Float16* __restrict__ wt, int Kp, int nbase, int l16, int q,
                 f16x8 f[NK][2]) {
#pragma unroll
    for (int nt = 0; nt < 2; ++nt) {
        int n = nbase + nt * 16 + l16;
#pragma unroll
        for (int ks = 0; ks < NK; ++ks)
            f[ks][nt] = *(const f16x8*)(wt + n * Kp + ks * 32 + q * 8);
    }
}

// Layers 0/1 over MH 16-row groups: D' = W^T X^T; relu'd f16 to H (stride 136).
template <int NK0, int MH>
DI void l01(const f16x8 (*w0f)[2], const f16x8 (*w1f)[2],
            const _Float16* __restrict__ X, int xstride,
            _Float16* __restrict__ H0, _Float16* __restrict__ H1,
            int l16, int w, int q) {
    const f32x4 zero = {0.f, 0.f, 0.f, 0.f};
    f32x4 acc[2][MH];
#pragma unroll
    for (int nt = 0; nt < 2; ++nt)
#pragma unroll
        for (int mt = 0; mt < MH; ++mt) acc[nt][mt] = zero;
#pragma unroll
    for (int ks = 0; ks < NK0; ++ks) {
        f16x8 x[MH];
#pragma unroll
        for (int mt = 0; mt < MH; ++mt)
            x[mt] = *(const f16x8*)(X + (mt * 16 + l16) * xstride + ks * 32 + q * 8);
#pragma unroll
        for (int nt = 0; nt < 2; ++nt)
#pragma unroll
            for (int mt = 0; mt < MH; ++mt)
                acc[nt][mt] = mfma16(w0f[ks][nt], x[mt], acc[nt][mt]);
    }
#pragma unroll
    for (int mt = 0; mt < MH; ++mt)
#pragma unroll
        for (int nt = 0; nt < 2; ++nt) {
            f16x4 h;
#pragma unroll
            for (int i = 0; i < 4; ++i) h[i] = (_Float16)fmaxf(acc[nt][mt][i], 0.f);
            *(f16x4*)(H0 + (mt * 16 + l16) * 136 + w * 32 + nt * 16 + q * 4) = h;
        }
    BAR();
    f32x4 a1[2][MH];
#pragma unroll
    for (int nt = 0; nt < 2; ++nt)
#pragma unroll
        for (int mt = 0; mt < MH; ++mt) a1[nt][mt] = zero;
#pragma unroll
    for (int ks = 0; ks < 4; ++ks) {
        f16x8 x[MH];
#pragma unroll
        for (int mt = 0; mt < MH; ++mt)
            x[mt] = *(const f16x8*)(H0 + (mt * 16 + l16) * 136 + ks * 32 + q * 8);
#pragma unroll
        for (int nt = 0; nt < 2; ++nt)
#pragma unroll
            for (int mt = 0; mt < MH; ++mt)
                a1[nt][mt] = mfma16(w1f[ks][nt], x[mt], a1[nt][mt]);
    }
#pragma unroll
    for (int mt = 0; mt < MH; ++mt)
#pragma unroll
        for (int nt = 0; nt < 2; ++nt) {
            f16x4 h;
#pragma unroll
            for (int i = 0; i < 4; ++i) h[i] = (_Float16)fmaxf(a1[nt][mt][i], 0.f);
            *(f16x4*)(H1 + (mt * 16 + l16) * 136 + w * 32 + nt * 16 + q * 4) = h;
        }
    BAR();
}

// Layer 2, row group g: rows (w>>1)*16 + l16 + 32*g, cols (w&1)*16 + q*4 + i.
DI f32x4 l2g(const f16x8* w2f, const _Float16* __restrict__ H1, int l16, int w,
             int q, int g) {
    int m = (w >> 1) * 16 + l16 + 32 * g;
    f32x4 acc = {0.f, 0.f, 0.f, 0.f};
#pragma unroll
    for (int ks = 0; ks < 4; ++ks) {
        f16x8 x = *(const f16x8*)(H1 + m * 136 + ks * 32 + q * 8);
        acc = mfma16(w2f[ks], x, acc);
    }
    return acc;
}

// ---------------- weight prep: fp32 [K][N] -> f16 W^T [Np][Kp] (zero padded) ----
struct WPtrs { const float* p[15]; };

__global__ void k_prep(WPtrs wp, _Float16* __restrict__ ws) {
    int b = blockIdx.x;
    const float* src; int K, N, Np, Kp, off;
    if (b == 0)       { src = wp.p[0];  K = 3;   N = 128; Np = 128; Kp = 32;  off = 0; }
    else if (b == 1)  { src = wp.p[1];  K = 128; N = 128; Np = 128; Kp = 128; off = 4096; }
    else if (b == 2)  { src = wp.p[2];  K = 128; N = 32;  Np = 32;  Kp = 128; off = 20480; }
    else if (b == 3)  { src = wp.p[3];  K = 3;   N = 128; Np = 128; Kp = 32;  off = 24576; }
    else if (b == 4)  { src = wp.p[4];  K = 128; N = 128; Np = 128; Kp = 128; off = 28672; }
    else if (b == 5)  { src = wp.p[5];  K = 128; N = 32;  Np = 32;  Kp = 128; off = 45056; }
    else if (b <= 9)  { int t = b - 6;  src = wp.p[6] + t * 12288;  K = 96;  N = 128; Np = 128; Kp = 96;  off = 49152 + t * 32768; }
    else if (b <= 13) { int t = b - 10; src = wp.p[7] + t * 16384;  K = 128; N = 128; Np = 128; Kp = 128; off = 61440 + t * 32768; }
    else if (b <= 17) { int t = b - 14; src = wp.p[8] + t * 4096;   K = 128; N = 32;  Np = 32;  Kp = 128; off = 77824 + t * 32768; }
    else if (b <= 21) { int t = b - 18; src = wp.p[9] + t * 8192;   K = 64;  N = 128; Np = 128; Kp = 64;  off = 180224 + t * 28672; }
    else if (b <= 25) { int t = b - 22; src = wp.p[10] + t * 16384; K = 128; N = 128; Np = 128; Kp = 128; off = 188416 + t * 28672; }
    else if (b <= 29) { int t = b - 26; src = wp.p[11] + t * 4096;  K = 128; N = 32;  Np = 32;  Kp = 128; off = 204800 + t * 28672; }
    else if (b == 30) { src = wp.p[12]; K = 32;  N = 128; Np = 128; Kp = 32;  off = 294912; }
    else if (b == 31) { src = wp.p[13]; K = 128; N = 128; Np = 128; Kp = 128; off = 299008; }
    else              { src = wp.p[14]; K = 128; N = 1;   Np = 16;  Kp = 128; off = 315392; }
    int total = Np * Kp;
    for (int i = threadIdx.x; i < total; i += 256) {
        int n = i / Kp, k = i - n * Kp;
        float v = (k < K && n < N) ? src[k * N + n] : 0.f;
        ws[off + i] = (_Float16)v;
    }
}

// ---------------- CSR build: histogram -> scan -> scatter (u32 atomics only) -----
__global__ void k_zero(unsigned* __restrict__ p, int n) {
    int i = blockIdx.x * 256 + threadIdx.x;
    if (i < n) p[i] = 0u;
}
__global__ void k_hist(const int* __restrict__ gi, unsigned* __restrict__ cnt) {
    int e = blockIdx.x * 256 + threadIdx.x;
    if (e < 512000) atomicAdd(&cnt[gi[2 * e + 1]], 1u);
}
// one block, 1024 threads: exclusive scan of cnt[0..32000) via Kogge-Stone.
__global__ __launch_bounds__(1024) void k_scan(
    const unsigned* __restrict__ cnt, unsigned* __restrict__ rowptr,
    unsigned* __restrict__ cursor) {
    __shared__ unsigned s[1024];
    int t = threadIdx.x;
    unsigned loc[32];
    unsigned sum = 0;
#pragma unroll
    for (int i = 0; i < 32; ++i) {
        int idx = t * 32 + i;
        unsigned v = (idx < 32000) ? cnt[idx] : 0u;
        loc[i] = v; sum += v;
    }
    s[t] = sum;
    __syncthreads();
#pragma unroll
    for (int d = 1; d < 1024; d <<= 1) {
        unsigned x = (t >= d) ? s[t - d] : 0u;
        __syncthreads();
        s[t] += x;
        __syncthreads();
    }
    if (t == 1023) rowptr[32000] = s[1023];
    unsigned off = (t == 0) ? 0u : s[t - 1];
#pragma unroll
    for (int i = 0; i < 32; ++i) {
        int idx = t * 32 + i;
        if (idx < 32000) { rowptr[idx] = off; cursor[idx] = off; off += loc[i]; }
    }
}
__global__ void k_scatter(const int* __restrict__ gi, unsigned* __restrict__ cursor,
                          unsigned* __restrict__ iperm, int2* __restrict__ sr) {
    int e = blockIdx.x * 256 + threadIdx.x;
    if (e < 512000) {
        int s = gi[2 * e], r = gi[2 * e + 1];
        unsigned pos = atomicAdd(&cursor[r], 1u);
        iperm[pos] = (unsigned)e;
        sr[pos] = make_int2(s, r);
    }
}

// ---------------- encoder: fp32 [M][3] -> MLP -> f16 out rows (64-row tiles) -----
// iperm != nullptr (edge path): row p of out corresponds to original edge iperm[p].
__global__ __launch_bounds__(256, 3) void k_enc(
    const float* __restrict__ in, _Float16* __restrict__ out,
    const _Float16* __restrict__ w0t, const _Float16* __restrict__ w1t,
    const _Float16* __restrict__ w2t, int NT, const unsigned* __restrict__ iperm) {
    __shared__ __align__(16) _Float16 Xp[64 * 40];
    __shared__ __align__(16) _Float16 H0[64 * 136];
    __shared__ __align__(16) _Float16 H1[64 * 136];
    const int tid = threadIdx.x, w = tid >> 6, lane = tid & 63;
    const int q = lane >> 4, l16 = lane & 15;
    f16x8 w0f[1][2], w1f[4][2], w2f[4];
    load_wf2<1>(w0t, 32, w * 32, l16, q, w0f);
    load_wf2<4>(w1t, 128, w * 32, l16, q, w1f);
    {
        int n2 = (w & 1) * 16 + l16;
#pragma unroll
        for (int ks = 0; ks < 4; ++ks)
            w2f[ks] = *(const f16x8*)(w2t + n2 * 128 + ks * 32 + q * 8);
    }
    for (int c = tid; c < 2560; c += 256) Xp[c] = (_Float16)0.f;
    BAR();

    const int g = gridDim.x;
    const int dr = tid / 3, dc = tid - dr * 3;  // valid when tid<192
    const int orow = (w >> 1) * 16 + l16, ocol = (w & 1) * 16 + q * 4;
    int t = blockIdx.x;
    int tn = t + g; if (tn >= NT) tn = t;
    float v = 0.f;
    if (tid < 192) {
        unsigned e = iperm ? iperm[t * 64 + dr] : (unsigned)(t * 64 + dr);
        v = in[e * 3 + dc];
    }

    while (true) {
        if (tid < 192) Xp[dr * 40 + dc] = (_Float16)v;
        BAR();
        float vn = 0.f;
        if (tid < 192) {
            unsigned e = iperm ? iperm[tn * 64 + dr] : (unsigned)(tn * 64 + dr);
            vn = in[e * 3 + dc];
        }
        l01<1, 4>(w0f, w1f, Xp, 40, H0, H1, l16, w, q);
#pragma unroll
        for (int gg = 0; gg < 2; ++gg) {
            f32x4 o = l2g(w2f, H1, l16, w, q, gg);
            f16x4 ov;
#pragma unroll
            for (int i = 0; i < 4; ++i) ov[i] = (_Float16)o[i];
            *(f16x4*)(out + (t * 64 + gg * 32 + orow) * 32 + ocol) = ov;
        }
        if (tn == t) break;
        t = tn; tn = t + g; if (tn >= NT) tn = t;
        v = vn;
    }
}

// ---------------- edge update: [edge|node_s|node_r](96) -> MLP -> +res -----------
// 64-row tiles. f16 latents, receiver-sorted rows, sr read sequentially.
// Staging: 64 rows x 12 int4 chunks = 768 = exactly 3 per thread.
__global__ __launch_bounds__(256, 3) void k_edge(
    const _Float16* __restrict__ node, _Float16* __restrict__ edgeP,
    const int2* __restrict__ sr,
    const _Float16* __restrict__ w0t, const _Float16* __restrict__ w1t,
    const _Float16* __restrict__ w2t) {
    __shared__ __align__(16) _Float16 Xe[64 * 104];
    __shared__ __align__(16) _Float16 H0[64 * 136];
    __shared__ __align__(16) _Float16 H1[64 * 136];
    const int tid = threadIdx.x, w = tid >> 6, lane = tid & 63;
    const int q = lane >> 4, l16 = lane & 15;
    f16x8 w0f[3][2], w1f[4][2], w2f[4];
    load_wf2<3>(w0t, 96, w * 32, l16, q, w0f);
    load_wf2<4>(w1t, 128, w * 32, l16, q, w1f);
    {
        int n2 = (w & 1) * 16 + l16;
#pragma unroll
        for (int ks = 0; ks < 4; ++ks)
            w2f[ks] = *(const f16x8*)(w2t + n2 * 128 + ks * 32 + q * 8);
    }
    int cr[3], cs[3];
#pragma unroll
    for (int j = 0; j < 3; ++j) {
        int c = tid + 256 * j;
        cr[j] = c / 12; cs[j] = c - cr[j] * 12;
    }
    const int orow = (w >> 1) * 16 + l16, ocol = (w & 1) * 16 + q * 4;

    const int NT = 8000, g = gridDim.x;
    int t = blockIdx.x;
    int tn = t + g; if (tn >= NT) tn = t;

    int2 srn[3]; int4 v[3]; f16x4 oldv[2];
    {
        int2 sr0[3];
#pragma unroll
        for (int j = 0; j < 3; ++j) sr0[j] = sr[t * 64 + cr[j]];
#pragma unroll
        for (int j = 0; j < 3; ++j) {
            int s = cs[j];
            const _Float16* src = (s < 4) ? edgeP + (t * 64 + cr[j]) * 32 + s * 8
                               : (s < 8) ? node + sr0[j].x * 32 + (s - 4) * 8
                                         : node + sr0[j].y * 32 + (s - 8) * 8;
            v[j] = *(const int4*)src;
        }
#pragma unroll
        for (int gg = 0; gg < 2; ++gg)
            oldv[gg] = *(const f16x4*)(edgeP + (t * 64 + gg * 32 + orow) * 32 + ocol);
#pragma unroll
        for (int j = 0; j < 3; ++j) srn[j] = sr[tn * 64 + cr[j]];
    }

    while (true) {
#pragma unroll
        for (int j = 0; j < 3; ++j)
            *(int4*)(Xe + cr[j] * 104 + cs[j] * 8) = v[j];
        BAR();
        int tn2 = tn + g; if (tn2 >= NT) tn2 = tn;
        int4 vn[3]; f16x4 oldn[2]; int2 sr2[3];
#pragma unroll
        for (int j = 0; j < 3; ++j) {
            int s = cs[j];
            const _Float16* src = (s < 4) ? edgeP + (tn * 64 + cr[j]) * 32 + s * 8
                               : (s < 8) ? node + srn[j].x * 32 + (s - 4) * 8
                                         : node + srn[j].y * 32 + (s - 8) * 8;
            vn[j] = *(const int4*)src;
        }
#pragma unroll
        for (int gg = 0; gg < 2; ++gg)
            oldn[gg] = *(const f16x4*)(edgeP + (tn * 64 + gg * 32 + orow) * 32 + ocol);
#pragma unroll
        for (int j = 0; j < 3; ++j) sr2[j] = sr[tn2 * 64 + cr[j]];

        l01<3, 4>(w0f, w1f, Xe, 104, H0, H1, l16, w, q);
#pragma unroll
        for (int gg = 0; gg < 2; ++gg) {
            f32x4 o = l2g(w2f, H1, l16, w, q, gg);
            f16x4 nv;
#pragma unroll
            for (int i = 0; i < 4; ++i) nv[i] = (_Float16)(o[i] + (float)oldv[gg][i]);
            *(f16x4*)(edgeP + (t * 64 + gg * 32 + orow) * 32 + ocol) = nv;
        }

        if (tn == t) break;
        t = tn; tn = tn2;
#pragma unroll
        for (int j = 0; j < 3; ++j) { v[j] = vn[j]; srn[j] = sr2[j]; }
        oldv[0] = oldn[0]; oldv[1] = oldn[1];
    }
}

// ---------------- node update: [node|csr_sum(edgeP)](64) -> MLP -> +res ----------
// One 32-row tile per block. Aggregation = contiguous fp32 segment sum (f16 rows).
__global__ __launch_bounds__(256, 3) void k_node(
    _Float16* __restrict__ node, const _Float16* __restrict__ edgeP,
    const unsigned* __restrict__ rowptr,
    const _Float16* __restrict__ w0t, const _Float16* __restrict__ w1t,
    const _Float16* __restrict__ w2t) {
    __shared__ __align__(16) _Float16 Xn[32 * 72];
    __shared__ __align__(16) _Float16 H0[32 * 136];
    __shared__ __align__(16) _Float16 H1[32 * 136];
    const int tid = threadIdx.x, w = tid >> 6, lane = tid & 63;
    const int q = lane >> 4, l16 = lane & 15;
    f16x8 w0f[2][2], w1f[4][2], w2f[4];
    load_wf2<2>(w0t, 64, w * 32, l16, q, w0f);
    load_wf2<4>(w1t, 128, w * 32, l16, q, w1f);
    {
        int n2 = (w & 1) * 16 + l16;
#pragma unroll
        for (int ks = 0; ks < 4; ++ks)
            w2f[ks] = *(const f16x8*)(w2t + n2 * 128 + ks * 32 + q * 8);
    }
    const int t = blockIdx.x;
    const int orow = (w >> 1) * 16 + l16, ocol = (w & 1) * 16 + q * 4;
    f16x4 oldv = *(const f16x4*)(node + (t * 32 + orow) * 32 + ocol);
    // 8 chunks/row (16 B each): cs<4 node copy, cs>=4 segment-sum of edgeP chunk
    {
        int cr = tid >> 3, cs = tid & 7;
        int r = t * 32 + cr;
        if (cs < 4) {
            *(int4*)(Xn + cr * 72 + cs * 8) = *(const int4*)(node + r * 32 + cs * 8);
        } else {
            unsigned b = rowptr[r], e = rowptr[r + 1];
            const _Float16* base = edgeP + (cs - 4) * 8;
            float a0[8], a1[8];
#pragma unroll
            for (int i = 0; i < 8; ++i) { a0[i] = 0.f; a1[i] = 0.f; }
            unsigned p = b;
            for (; p + 2 <= e; p += 2) {
                f16x8 x0 = *(const f16x8*)(base + (p + 0) * 32);
                f16x8 x1 = *(const f16x8*)(base + (p + 1) * 32);
#pragma unroll
                for (int i = 0; i < 8; ++i) { a0[i] += (float)x0[i]; a1[i] += (float)x1[i]; }
            }
            if (p < e) {
                f16x8 x0 = *(const f16x8*)(base + p * 32);
#pragma unroll
                for (int i = 0; i < 8; ++i) a0[i] += (float)x0[i];
            }
            f16x8 h;
#pragma unroll
            for (int i = 0; i < 8; ++i) h[i] = (_Float16)(a0[i] + a1[i]);
            *(f16x8*)(Xn + cr * 72 + cs * 8) = h;
        }
    }
    BAR();
    l01<2, 2>(w0f, w1f, Xn, 72, H0, H1, l16, w, q);
    f32x4 o = l2g(w2f, H1, l16, w, q, 0);
    f16x4 nv;
#pragma unroll
    for (int i = 0; i < 4; ++i) nv[i] = (_Float16)(o[i] + (float)oldv[i]);
    *(f16x4*)(node + (t * 32 + orow) * 32 + ocol) = nv;
}

// ---------------- decoder: node(32) -> MLP(32->128->128->1) -> fp32 out ----------
__global__ __launch_bounds__(256, 3) void k_dec(
    const _Float16* __restrict__ node,
    const _Float16* __restrict__ w0t, const _Float16* __restrict__ w1t,
    const _Float16* __restrict__ w2t, float* __restrict__ out) {
    __shared__ __align__(16) _Float16 Xd[64 * 40];
    __shared__ __align__(16) _Float16 H0[64 * 136];
    __shared__ __align__(16) _Float16 H1[64 * 136];
    const int tid = threadIdx.x, w = tid >> 6, lane = tid & 63;
    const int q = lane >> 4, l16 = lane & 15;
    f16x8 w0f[1][2], w1f[4][2], w2f[4];
    load_wf2<1>(w0t, 32, w * 32, l16, q, w0f);
    load_wf2<4>(w1t, 128, w * 32, l16, q, w1f);
    {
        int n2 = l16;  // padded W2^T is [16][128]; all waves load tile 0
#pragma unroll
        for (int ks = 0; ks < 4; ++ks)
            w2f[ks] = *(const f16x8*)(w2t + n2 * 128 + ks * 32 + q * 8);
    }
    const int t = blockIdx.x;
    {
        int cr = tid >> 2, cs = tid & 3;
        *(int4*)(Xd + cr * 40 + cs * 8) = *(const int4*)(node + (t * 64 + cr) * 32 + cs * 8);
    }
    BAR();
    l01<1, 4>(w0f, w1f, Xd, 40, H0, H1, l16, w, q);
#pragma unroll
    for (int gg = 0; gg < 2; ++gg) {
        f32x4 o = l2g(w2f, H1, l16, w, q, gg);
        // only col 0 is real: waves with (w&1)==0, lanes q==0, reg 0
        if ((w & 1) == 0 && q == 0) out[t * 64 + gg * 32 + (w >> 1) * 16 + l16] = o[0];
    }
}

extern "C" void kernel_launch(void* const* d_in, const int* in_sizes, int n_in,
                              void* d_out, int out_size, void* d_ws, size_t ws_size,
                              hipStream_t stream) {
    const float* input_node = (const float*)d_in[0];
    const float* input_edge = (const float*)d_in[1];
    const int* gi = (const int*)d_in[2];

    _Float16* ws = (_Float16*)d_ws;
    // ws layout (bytes):
    //   weights f16:         [0,          634,880)
    //   node  f16 32000x32:  [655,360,    2,703,360)
    //   edgeP f16 512000x32: [2,703,360,  35,471,360)   (receiver-sorted rows)
    //   rowptr u32[32001]:   [35,471,360, 35,599,364)
    //   cursor u32[32000]:   [35,599,616, 35,727,616)
    //   iperm  u32[512000]:  [35,727,616, 37,775,616)
    //   sr   int2[512000]:   [37,775,616, 41,871,616)
    _Float16* node = (_Float16*)((char*)d_ws + 655360);
    _Float16* edgeP = (_Float16*)((char*)d_ws + 2703360);
    unsigned* rowptr = (unsigned*)((char*)d_ws + 35471360);
    unsigned* cursor = (unsigned*)((char*)d_ws + 35599616);
    unsigned* iperm = (unsigned*)((char*)d_ws + 35727616);
    int2* sr = (int2*)((char*)d_ws + 37775616);

    WPtrs wp;
    for (int i = 0; i < 15; ++i) wp.p[i] = (const float*)d_in[3 + i];

    k_prep<<<33, 256, 0, stream>>>(wp, ws);

    // CSR build (u32 atomics only)
    k_zero<<<125, 256, 0, stream>>>(cursor, 32000);
    k_hist<<<2000, 256, 0, stream>>>(gi, cursor);
    k_scan<<<1, 1024, 0, stream>>>(cursor, rowptr, cursor);
    k_scatter<<<2000, 256, 0, stream>>>(gi, cursor, iperm, sr);

    k_enc<<<500, 256, 0, stream>>>(input_node, node, ws + 0, ws + 4096, ws + 20480,
                                   500, nullptr);
    k_enc<<<768, 256, 0, stream>>>(input_edge, edgeP, ws + 24576, ws + 28672,
                                   ws + 45056, 8000, iperm);

    for (int t = 0; t < 4; ++t) {
        k_edge<<<768, 256, 0, stream>>>(node, edgeP, sr,
                                        ws + 49152 + t * 32768,
                                        ws + 61440 + t * 32768,
                                        ws + 77824 + t * 32768);
        k_node<<<1000, 256, 0, stream>>>(node, edgeP, rowptr,
                                         ws + 180224 + t * 28672,
                                         ws + 188416 + t * 28672,
                                         ws + 204800 + t * 28672);
    }
    k_dec<<<500, 256, 0, stream>>>(node, ws + 294912, ws + 299008, ws + 315392,
                                   (float*)d_out);
}

// Round 10
// 503.933 us; speedup vs baseline: 3.2244x; 1.2766x over previous
//
#include <hip/hip_runtime.h>

typedef __attribute__((ext_vector_type(8))) _Float16 f16x8;
typedef __attribute__((ext_vector_type(4))) _Float16 f16x4;
typedef __attribute__((ext_vector_type(4))) float f32x4;

#define DI __device__ __forceinline__
// Raw barrier: LDS-drain only (lgkmcnt). Avoids the compiler's vmcnt(0) drain.
#define BAR() asm volatile("s_waitcnt lgkmcnt(0)\n\ts_barrier" ::: "memory")

DI f32x4 mfma16(f16x8 a, f16x8 b, f32x4 c) {
    return __builtin_amdgcn_mfma_f32_16x16x32_f16(a, b, c, 0, 0, 0);
}

// Wave-mapping: wave w owns features [w*32, w*32+32) for layers 0/1 (2 n-tiles,
// weight frags reused across all MH m-groups of 16 rows). Layer 2: wave w computes
// rows (w>>1)*16 (+32*g) and cols (w&1)*16 of the MHx16 x 32 output.

template <int NK>
DI void load_wf2(const _Float16* __restrict__ wt, int Kp, int nbase, int l16, int q,
                 f16x8 f[NK][2]) {
#pragma unroll
    for (int nt = 0; nt < 2; ++nt) {
        int n = nbase + nt * 16 + l16;
#pragma unroll
        for (int ks = 0; ks < NK; ++ks)
            f[ks][nt] = *(const f16x8*)(wt + n * Kp + ks * 32 + q * 8);
    }
}

// Layers 0/1 over MH 16-row groups: D' = W^T X^T; relu'd f16 to H (stride 136).
template <int NK0, int MH>
DI void l01(const f16x8 (*w0f)[2], const f16x8 (*w1f)[2],
            const _Float16* __restrict__ X, int xstride,
            _Float16* __restrict__ H0, _Float16* __restrict__ H1,
            int l16, int w, int q) {
    const f32x4 zero = {0.f, 0.f, 0.f, 0.f};
    f32x4 acc[2][MH];
#pragma unroll
    for (int nt = 0; nt < 2; ++nt)
#pragma unroll
        for (int mt = 0; mt < MH; ++mt) acc[nt][mt] = zero;
#pragma unroll
    for (int ks = 0; ks < NK0; ++ks) {
        f16x8 x[MH];
#pragma unroll
        for (int mt = 0; mt < MH; ++mt)
            x[mt] = *(const f16x8*)(X + (mt * 16 + l16) * xstride + ks * 32 + q * 8);
#pragma unroll
        for (int nt = 0; nt < 2; ++nt)
#pragma unroll
            for (int mt = 0; mt < MH; ++mt)
                acc[nt][mt] = mfma16(w0f[ks][nt], x[mt], acc[nt][mt]);
    }
#pragma unroll
    for (int mt = 0; mt < MH; ++mt)
#pragma unroll
        for (int nt = 0; nt < 2; ++nt) {
            f16x4 h;
#pragma unroll
            for (int i = 0; i < 4; ++i) h[i] = (_Float16)fmaxf(acc[nt][mt][i], 0.f);
            *(f16x4*)(H0 + (mt * 16 + l16) * 136 + w * 32 + nt * 16 + q * 4) = h;
        }
    BAR();
    f32x4 a1[2][MH];
#pragma unroll
    for (int nt = 0; nt < 2; ++nt)
#pragma unroll
        for (int mt = 0; mt < MH; ++mt) a1[nt][mt] = zero;
#pragma unroll
    for (int ks = 0; ks < 4; ++ks) {
        f16x8 x[MH];
#pragma unroll
        for (int mt = 0; mt < MH; ++mt)
            x[mt] = *(const f16x8*)(H0 + (mt * 16 + l16) * 136 + ks * 32 + q * 8);
#pragma unroll
        for (int nt = 0; nt < 2; ++nt)
#pragma unroll
            for (int mt = 0; mt < MH; ++mt)
                a1[nt][mt] = mfma16(w1f[ks][nt], x[mt], a1[nt][mt]);
    }
#pragma unroll
    for (int mt = 0; mt < MH; ++mt)
#pragma unroll
        for (int nt = 0; nt < 2; ++nt) {
            f16x4 h;
#pragma unroll
            for (int i = 0; i < 4; ++i) h[i] = (_Float16)fmaxf(a1[nt][mt][i], 0.f);
            *(f16x4*)(H1 + (mt * 16 + l16) * 136 + w * 32 + nt * 16 + q * 4) = h;
        }
    BAR();
}

// Layer 2, row group g: rows (w>>1)*16 + l16 + 32*g, cols (w&1)*16 + q*4 + i.
DI f32x4 l2g(const f16x8* w2f, const _Float16* __restrict__ H1, int l16, int w,
             int q, int g) {
    int m = (w >> 1) * 16 + l16 + 32 * g;
    f32x4 acc = {0.f, 0.f, 0.f, 0.f};
#pragma unroll
    for (int ks = 0; ks < 4; ++ks) {
        f16x8 x = *(const f16x8*)(H1 + m * 136 + ks * 32 + q * 8);
        acc = mfma16(w2f[ks], x, acc);
    }
    return acc;
}

// ---------------- weight prep: fp32 [K][N] -> f16 W^T [Np][Kp] (zero padded) ----
struct WPtrs { const float* p[15]; };

__global__ void k_prep(WPtrs wp, _Float16* __restrict__ ws) {
    int b = blockIdx.x;
    const float* src; int K, N, Np, Kp, off;
    if (b == 0)       { src = wp.p[0];  K = 3;   N = 128; Np = 128; Kp = 32;  off = 0; }
    else if (b == 1)  { src = wp.p[1];  K = 128; N = 128; Np = 128; Kp = 128; off = 4096; }
    else if (b == 2)  { src = wp.p[2];  K = 128; N = 32;  Np = 32;  Kp = 128; off = 20480; }
    else if (b == 3)  { src = wp.p[3];  K = 3;   N = 128; Np = 128; Kp = 32;  off = 24576; }
    else if (b == 4)  { src = wp.p[4];  K = 128; N = 128; Np = 128; Kp = 128; off = 28672; }
    else if (b == 5)  { src = wp.p[5];  K = 128; N = 32;  Np = 32;  Kp = 128; off = 45056; }
    else if (b <= 9)  { int t = b - 6;  src = wp.p[6] + t * 12288;  K = 96;  N = 128; Np = 128; Kp = 96;  off = 49152 + t * 32768; }
    else if (b <= 13) { int t = b - 10; src = wp.p[7] + t * 16384;  K = 128; N = 128; Np = 128; Kp = 128; off = 61440 + t * 32768; }
    else if (b <= 17) { int t = b - 14; src = wp.p[8] + t * 4096;   K = 128; N = 32;  Np = 32;  Kp = 128; off = 77824 + t * 32768; }
    else if (b <= 21) { int t = b - 18; src = wp.p[9] + t * 8192;   K = 64;  N = 128; Np = 128; Kp = 64;  off = 180224 + t * 28672; }
    else if (b <= 25) { int t = b - 22; src = wp.p[10] + t * 16384; K = 128; N = 128; Np = 128; Kp = 128; off = 188416 + t * 28672; }
    else if (b <= 29) { int t = b - 26; src = wp.p[11] + t * 4096;  K = 128; N = 32;  Np = 32;  Kp = 128; off = 204800 + t * 28672; }
    else if (b == 30) { src = wp.p[12]; K = 32;  N = 128; Np = 128; Kp = 32;  off = 294912; }
    else if (b == 31) { src = wp.p[13]; K = 128; N = 128; Np = 128; Kp = 128; off = 299008; }
    else              { src = wp.p[14]; K = 128; N = 1;   Np = 16;  Kp = 128; off = 315392; }
    int total = Np * Kp;
    for (int i = threadIdx.x; i < total; i += 256) {
        int n = i / Kp, k = i - n * Kp;
        float v = (k < K && n < N) ? src[k * N + n] : 0.f;
        ws[off + i] = (_Float16)v;
    }
}

// ---------------- CSR build: histogram -> scan -> scatter (u32 atomics only) -----
__global__ void k_zero(unsigned* __restrict__ p, int n) {
    int i = blockIdx.x * 256 + threadIdx.x;
    if (i < n) p[i] = 0u;
}
__global__ void k_hist(const int* __restrict__ gi, unsigned* __restrict__ cnt) {
    int e = blockIdx.x * 256 + threadIdx.x;
    if (e < 512000) atomicAdd(&cnt[gi[2 * e + 1]], 1u);
}
// one block, 1024 threads: exclusive scan of cnt[0..32000) via Kogge-Stone.
__global__ __launch_bounds__(1024) void k_scan(
    const unsigned* __restrict__ cnt, unsigned* __restrict__ rowptr,
    unsigned* __restrict__ cursor) {
    __shared__ unsigned s[1024];
    int t = threadIdx.x;
    unsigned loc[32];
    unsigned sum = 0;
#pragma unroll
    for (int i = 0; i < 32; ++i) {
        int idx = t * 32 + i;
        unsigned v = (idx < 32000) ? cnt[idx] : 0u;
        loc[i] = v; sum += v;
    }
    s[t] = sum;
    __syncthreads();
#pragma unroll
    for (int d = 1; d < 1024; d <<= 1) {
        unsigned x = (t >= d) ? s[t - d] : 0u;
        __syncthreads();
        s[t] += x;
        __syncthreads();
    }
    if (t == 1023) rowptr[32000] = s[1023];
    unsigned off = (t == 0) ? 0u : s[t - 1];
#pragma unroll
    for (int i = 0; i < 32; ++i) {
        int idx = t * 32 + i;
        if (idx < 32000) { rowptr[idx] = off; cursor[idx] = off; off += loc[i]; }
    }
}
__global__ void k_scatter(const int* __restrict__ gi, unsigned* __restrict__ cursor,
                          unsigned* __restrict__ iperm, int2* __restrict__ sr) {
    int e = blockIdx.x * 256 + threadIdx.x;
    if (e < 512000) {
        int s = gi[2 * e], r = gi[2 * e + 1];
        unsigned pos = atomicAdd(&cursor[r], 1u);
        iperm[pos] = (unsigned)e;
        sr[pos] = make_int2(s, r);
    }
}

// ---------------- encoder: fp32 [M][3] -> MLP -> f16 out rows (64-row tiles) -----
__global__ __launch_bounds__(256, 3) void k_enc(
    const float* __restrict__ in, _Float16* __restrict__ out,
    const _Float16* __restrict__ w0t, const _Float16* __restrict__ w1t,
    const _Float16* __restrict__ w2t, int NT, const unsigned* __restrict__ iperm) {
    __shared__ __align__(16) _Float16 Xp[64 * 40];
    __shared__ __align__(16) _Float16 H0[64 * 136];
    __shared__ __align__(16) _Float16 H1[64 * 136];
    const int tid = threadIdx.x, w = tid >> 6, lane = tid & 63;
    const int q = lane >> 4, l16 = lane & 15;
    f16x8 w0f[1][2], w1f[4][2], w2f[4];
    load_wf2<1>(w0t, 32, w * 32, l16, q, w0f);
    load_wf2<4>(w1t, 128, w * 32, l16, q, w1f);
    {
        int n2 = (w & 1) * 16 + l16;
#pragma unroll
        for (int ks = 0; ks < 4; ++ks)
            w2f[ks] = *(const f16x8*)(w2t + n2 * 128 + ks * 32 + q * 8);
    }
    for (int c = tid; c < 2560; c += 256) Xp[c] = (_Float16)0.f;
    BAR();

    const int g = gridDim.x;
    const int dr = tid / 3, dc = tid - dr * 3;  // valid when tid<192
    const int orow = (w >> 1) * 16 + l16, ocol = (w & 1) * 16 + q * 4;
    int t = blockIdx.x;

    while (true) {
        if (tid < 192) {
            unsigned e = iperm ? iperm[t * 64 + dr] : (unsigned)(t * 64 + dr);
            Xp[dr * 40 + dc] = (_Float16)in[e * 3 + dc];
        }
        BAR();
        l01<1, 4>(w0f, w1f, Xp, 40, H0, H1, l16, w, q);
#pragma unroll
        for (int gg = 0; gg < 2; ++gg) {
            f32x4 o = l2g(w2f, H1, l16, w, q, gg);
            f16x4 ov;
#pragma unroll
            for (int i = 0; i < 4; ++i) ov[i] = (_Float16)o[i];
            *(f16x4*)(out + (t * 64 + gg * 32 + orow) * 32 + ocol) = ov;
        }
        t += g;
        if (t >= NT) break;
    }
}

// ---------------- edge update: [edge|node_s|node_r](96) -> MLP -> +res -----------
// 64-row tiles, f16 latents, receiver-sorted rows. No data pipeline (registers are
// the scarce resource: keep weights resident). Only sr is prefetched one tile ahead.
// Residual's old value is read from LDS (Xe cols 0..31) after the staging barrier.
__global__ __launch_bounds__(256, 3) void k_edge(
    const _Float16* __restrict__ node, _Float16* __restrict__ edgeP,
    const int2* __restrict__ sr,
    const _Float16* __restrict__ w0t, const _Float16* __restrict__ w1t,
    const _Float16* __restrict__ w2t) {
    __shared__ __align__(16) _Float16 Xe[64 * 104];
    __shared__ __align__(16) _Float16 H0[64 * 136];
    __shared__ __align__(16) _Float16 H1[64 * 136];
    const int tid = threadIdx.x, w = tid >> 6, lane = tid & 63;
    const int q = lane >> 4, l16 = lane & 15;
    f16x8 w0f[3][2], w1f[4][2], w2f[4];
    load_wf2<3>(w0t, 96, w * 32, l16, q, w0f);
    load_wf2<4>(w1t, 128, w * 32, l16, q, w1f);
    {
        int n2 = (w & 1) * 16 + l16;
#pragma unroll
        for (int ks = 0; ks < 4; ++ks)
            w2f[ks] = *(const f16x8*)(w2t + n2 * 128 + ks * 32 + q * 8);
    }
    int cr[3], cs[3];
#pragma unroll
    for (int j = 0; j < 3; ++j) {
        int c = tid + 256 * j;
        cr[j] = c / 12; cs[j] = c - cr[j] * 12;
    }
    const int orow = (w >> 1) * 16 + l16, ocol = (w & 1) * 16 + q * 4;

    const int NT = 8000, g = gridDim.x;
    int t = blockIdx.x;
    int2 srv[3];
#pragma unroll
    for (int j = 0; j < 3; ++j) srv[j] = sr[t * 64 + cr[j]];

    while (true) {
        int tn = t + g; if (tn >= NT) tn = t;
        // stage tile t (loads issue; Xe write waits on them via vmcnt)
        int4 v[3];
#pragma unroll
        for (int j = 0; j < 3; ++j) {
            int s = cs[j];
            const _Float16* src = (s < 4) ? edgeP + (t * 64 + cr[j]) * 32 + s * 8
                               : (s < 8) ? node + srv[j].x * 32 + (s - 4) * 8
                                         : node + srv[j].y * 32 + (s - 8) * 8;
            v[j] = *(const int4*)src;
        }
        int2 srn[3];
#pragma unroll
        for (int j = 0; j < 3; ++j) srn[j] = sr[tn * 64 + cr[j]];
#pragma unroll
        for (int j = 0; j < 3; ++j)
            *(int4*)(Xe + cr[j] * 104 + cs[j] * 8) = v[j];
        BAR();
        // old edge latent from LDS (cols 0..31 of the staged tile)
        f16x4 oldv[2];
#pragma unroll
        for (int gg = 0; gg < 2; ++gg)
            oldv[gg] = *(const f16x4*)(Xe + (gg * 32 + orow) * 104 + ocol);

        l01<3, 4>(w0f, w1f, Xe, 104, H0, H1, l16, w, q);
#pragma unroll
        for (int gg = 0; gg < 2; ++gg) {
            f32x4 o = l2g(w2f, H1, l16, w, q, gg);
            f16x4 nv;
#pragma unroll
            for (int i = 0; i < 4; ++i) nv[i] = (_Float16)(o[i] + (float)oldv[gg][i]);
            *(f16x4*)(edgeP + (t * 64 + gg * 32 + orow) * 32 + ocol) = nv;
        }

        if (tn == t) break;
        t = tn;
#pragma unroll
        for (int j = 0; j < 3; ++j) srv[j] = srn[j];
    }
}

// ---------------- node update: [node|csr_sum(edgeP)](64) -> MLP -> +res ----------
// One 32-row tile per block. Aggregation = contiguous fp32 segment sum (f16 rows).
// Old node latent read from LDS (Xn cols 0..31).
__global__ __launch_bounds__(256, 3) void k_node(
    _Float16* __restrict__ node, const _Float16* __restrict__ edgeP,
    const unsigned* __restrict__ rowptr,
    const _Float16* __restrict__ w0t, const _Float16* __restrict__ w1t,
    const _Float16* __restrict__ w2t) {
    __shared__ __align__(16) _Float16 Xn[32 * 72];
    __shared__ __align__(16) _Float16 H0[32 * 136];
    __shared__ __align__(16) _Float16 H1[32 * 136];
    const int tid = threadIdx.x, w = tid >> 6, lane = tid & 63;
    const int q = lane >> 4, l16 = lane & 15;
    f16x8 w0f[2][2], w1f[4][2], w2f[4];
    load_wf2<2>(w0t, 64, w * 32, l16, q, w0f);
    load_wf2<4>(w1t, 128, w * 32, l16, q, w1f);
    {
        int n2 = (w & 1) * 16 + l16;
#pragma unroll
        for (int ks = 0; ks < 4; ++ks)
            w2f[ks] = *(const f16x8*)(w2t + n2 * 128 + ks * 32 + q * 8);
    }
    const int t = blockIdx.x;
    const int orow = (w >> 1) * 16 + l16, ocol = (w & 1) * 16 + q * 4;
    // 8 chunks/row (16 B each): cs<4 node copy, cs>=4 segment-sum of edgeP chunk
    {
        int cr = tid >> 3, cs = tid & 7;
        int r = t * 32 + cr;
        if (cs < 4) {
            *(int4*)(Xn + cr * 72 + cs * 8) = *(const int4*)(node + r * 32 + cs * 8);
        } else {
            unsigned b = rowptr[r], e = rowptr[r + 1];
            const _Float16* base = edgeP + (cs - 4) * 8;
            float a0[8], a1[8];
#pragma unroll
            for (int i = 0; i < 8; ++i) { a0[i] = 0.f; a1[i] = 0.f; }
            unsigned p = b;
            for (; p + 2 <= e; p += 2) {
                f16x8 x0 = *(const f16x8*)(base + (p + 0) * 32);
                f16x8 x1 = *(const f16x8*)(base + (p + 1) * 32);
#pragma unroll
                for (int i = 0; i < 8; ++i) { a0[i] += (float)x0[i]; a1[i] += (float)x1[i]; }
            }
            if (p < e) {
                f16x8 x0 = *(const f16x8*)(base + p * 32);
#pragma unroll
                for (int i = 0; i < 8; ++i) a0[i] += (float)x0[i];
            }
            f16x8 h;
#pragma unroll
            for (int i = 0; i < 8; ++i) h[i] = (_Float16)(a0[i] + a1[i]);
            *(f16x8*)(Xn + cr * 72 + cs * 8) = h;
        }
    }
    BAR();
    f16x4 oldv = *(const f16x4*)(Xn + orow * 72 + ocol);
    l01<2, 2>(w0f, w1f, Xn, 72, H0, H1, l16, w, q);
    f32x4 o = l2g(w2f, H1, l16, w, q, 0);
    f16x4 nv;
#pragma unroll
    for (int i = 0; i < 4; ++i) nv[i] = (_Float16)(o[i] + (float)oldv[i]);
    *(f16x4*)(node + (t * 32 + orow) * 32 + ocol) = nv;
}

// ---------------- decoder: node(32) -> MLP(32->128->128->1) -> fp32 out ----------
__global__ __launch_bounds__(256, 3) void k_dec(
    const _Float16* __restrict__ node,
    const _Float16* __restrict__ w0t, const _Float16* __restrict__ w1t,
    const _Float16* __restrict__ w2t, float* __restrict__ out) {
    __shared__ __align__(16) _Float16 Xd[64 * 40];
    __shared__ __align__(16) _Float16 H0[64 * 136];
    __shared__ __align__(16) _Float16 H1[64 * 136];
    const int tid = threadIdx.x, w = tid >> 6, lane = tid & 63;
    const int q = lane >> 4, l16 = lane & 15;
    f16x8 w0f[1][2], w1f[4][2], w2f[4];
    load_wf2<1>(w0t, 32, w * 32, l16, q, w0f);
    load_wf2<4>(w1t, 128, w * 32, l16, q, w1f);
    {
        int n2 = l16;  // padded W2^T is [16][128]; all waves load tile 0
#pragma unroll
        for (int ks = 0; ks < 4; ++ks)
            w2f[ks] = *(const f16x8*)(w2t + n2 * 128 + ks * 32 + q * 8);
    }
    const int t = blockIdx.x;
    {
        int cr = tid >> 2, cs = tid & 3;
        *(int4*)(Xd + cr * 40 + cs * 8) = *(const int4*)(node + (t * 64 + cr) * 32 + cs * 8);
    }
    BAR();
    l01<1, 4>(w0f, w1f, Xd, 40, H0, H1, l16, w, q);
#pragma unroll
    for (int gg = 0; gg < 2; ++gg) {
        f32x4 o = l2g(w2f, H1, l16, w, q, gg);
        // only col 0 is real: waves with (w&1)==0, lanes q==0, reg 0
        if ((w & 1) == 0 && q == 0) out[t * 64 + gg * 32 + (w >> 1) * 16 + l16] = o[0];
    }
}

extern "C" void kernel_launch(void* const* d_in, const int* in_sizes, int n_in,
                              void* d_out, int out_size, void* d_ws, size_t ws_size,
                              hipStream_t stream) {
    const float* input_node = (const float*)d_in[0];
    const float* input_edge = (const float*)d_in[1];
    const int* gi = (const int*)d_in[2];

    _Float16* ws = (_Float16*)d_ws;
    // ws layout (bytes):
    //   weights f16:         [0,          634,880)
    //   node  f16 32000x32:  [655,360,    2,703,360)
    //   edgeP f16 512000x32: [2,703,360,  35,471,360)   (receiver-sorted rows)
    //   rowptr u32[32001]:   [35,471,360, 35,599,364)
    //   cursor u32[32000]:   [35,599,616, 35,727,616)
    //   iperm  u32[512000]:  [35,727,616, 37,775,616)
    //   sr   int2[512000]:   [37,775,616, 41,871,616)
    _Float16* node = (_Float16*)((char*)d_ws + 655360);
    _Float16* edgeP = (_Float16*)((char*)d_ws + 2703360);
    unsigned* rowptr = (unsigned*)((char*)d_ws + 35471360);
    unsigned* cursor = (unsigned*)((char*)d_ws + 35599616);
    unsigned* iperm = (unsigned*)((char*)d_ws + 35727616);
    int2* sr = (int2*)((char*)d_ws + 37775616);

    WPtrs wp;
    for (int i = 0; i < 15; ++i) wp.p[i] = (const float*)d_in[3 + i];

    k_prep<<<33, 256, 0, stream>>>(wp, ws);

    // CSR build (u32 atomics only)
    k_zero<<<125, 256, 0, stream>>>(cursor, 32000);
    k_hist<<<2000, 256, 0, stream>>>(gi, cursor);
    k_scan<<<1, 1024, 0, stream>>>(cursor, rowptr, cursor);
    k_scatter<<<2000, 256, 0, stream>>>(gi, cursor, iperm, sr);

    k_enc<<<500, 256, 0, stream>>>(input_node, node, ws + 0, ws + 4096, ws + 20480,
                                   500, nullptr);
    k_enc<<<768, 256, 0, stream>>>(input_edge, edgeP, ws + 24576, ws + 28672,
                                   ws + 45056, 8000, iperm);

    for (int t = 0; t < 4; ++t) {
        k_edge<<<768, 256, 0, stream>>>(node, edgeP, sr,
                                        ws + 49152 + t * 32768,
                                        ws + 61440 + t * 32768,
                                        ws + 77824 + t * 32768);
        k_node<<<1000, 256, 0, stream>>>(node, edgeP, rowptr,
                                         ws + 180224 + t * 28672,
                                         ws + 188416 + t * 28672,
                                         ws + 204800 + t * 28672);
    }
    k_dec<<<500, 256, 0, stream>>>(node, ws + 294912, ws + 299008, ws + 315392,
                                   (float*)d_out);
}